// Round 3
// baseline (1835.671 us; speedup 1.0000x reference)
//
#include <hip/hip_runtime.h>
#include <hip/hip_bf16.h>

#define D_MODEL 1024
#define D_INNER 2048
#define D_STATE 16
#define DT_RANK 64
#define BATCH 2
#define SEQLEN 4096
#define BL (BATCH * SEQLEN)           // 8192 rows (b,l)
#define NPROJ (DT_RANK + 2 * D_STATE) // 96
#define CH 64                         // scan chunk length
#define NCH (SEQLEN / CH)             // 64 chunks

__device__ __forceinline__ float sigmoidf_(float v) {
    return 1.0f / (1.0f + __expf(-v));
}

// ---------------------------------------------------------------------------
// Generic fp32 NT GEMM: C[M,N] = A[M,K] (row-major, lda) * B[N,K]^T (row-major, ldb)
// EPI: 0 = plain store, 1 = softplus(v + bias[n]), 2 = plain store with n<N guard
// Tile: 64x64, BK=16, 256 threads, 4x4 per thread, float4 global + LDS reads.
// ---------------------------------------------------------------------------
template <int EPI>
__global__ __launch_bounds__(256)
void gemm_nt(const float* __restrict__ A, const float* __restrict__ B,
             float* __restrict__ C, int M, int N, int K,
             int lda, int ldb, int ldc, const float* __restrict__ bias) {
    constexpr int BM = 64, BN = 64, BK = 16, PAD = 4;
    __shared__ float As[BK][BM + PAD];
    __shared__ float Bs[BK][BN + PAD];
    const int t = threadIdx.x;
    const int tx = t & 15, ty = t >> 4;
    const int m0 = blockIdx.y * BM, n0 = blockIdx.x * BN;
    const int lrow = t >> 2;        // 0..63
    const int lcol = (t & 3) * 4;   // 0,4,8,12

    float acc[4][4] = {{0.f}};

    for (int k0 = 0; k0 < K; k0 += BK) {
        float4 av = *reinterpret_cast<const float4*>(
            A + (size_t)(m0 + lrow) * lda + k0 + lcol);
        float4 bv;
        if (EPI != 2 || n0 + lrow < N)
            bv = *reinterpret_cast<const float4*>(
                B + (size_t)(n0 + lrow) * ldb + k0 + lcol);
        else
            bv = make_float4(0.f, 0.f, 0.f, 0.f);
        __syncthreads();  // previous tile's compute done before overwrite
        As[lcol + 0][lrow] = av.x; As[lcol + 1][lrow] = av.y;
        As[lcol + 2][lrow] = av.z; As[lcol + 3][lrow] = av.w;
        Bs[lcol + 0][lrow] = bv.x; Bs[lcol + 1][lrow] = bv.y;
        Bs[lcol + 2][lrow] = bv.z; Bs[lcol + 3][lrow] = bv.w;
        __syncthreads();
#pragma unroll
        for (int k = 0; k < BK; ++k) {
            float4 a = *reinterpret_cast<const float4*>(&As[k][ty * 4]);
            float4 b = *reinterpret_cast<const float4*>(&Bs[k][tx * 4]);
            float ar[4] = {a.x, a.y, a.z, a.w};
            float br[4] = {b.x, b.y, b.z, b.w};
#pragma unroll
            for (int i = 0; i < 4; ++i)
#pragma unroll
                for (int j = 0; j < 4; ++j)
                    acc[i][j] = fmaf(ar[i], br[j], acc[i][j]);
        }
    }

#pragma unroll
    for (int i = 0; i < 4; ++i) {
        const int m = m0 + ty * 4 + i;
#pragma unroll
        for (int j = 0; j < 4; ++j) {
            const int n = n0 + tx * 4 + j;
            if (EPI == 2 && n >= N) continue;
            float v = acc[i][j];
            if (EPI == 1) {
                v += bias[n];
                v = fmaxf(v, 0.f) + log1pf(__expf(-fabsf(v)));  // stable softplus
            }
            C[(size_t)m * ldc + n] = v;
        }
    }
}

// ---------------------------------------------------------------------------
// Depthwise causal conv (D_CONV=4) + bias + SiLU.
// xr: pre-conv x, layout (B, L, D_INNER). Output xc same layout.
// ---------------------------------------------------------------------------
__global__ __launch_bounds__(256)
void conv_silu_k(const float* __restrict__ xr, const float* __restrict__ cw,
                 const float* __restrict__ cb, float* __restrict__ xc) {
    const int idx = blockIdx.x * 256 + threadIdx.x;  // (b*L + l)*D_INNER + d
    const int d = idx & (D_INNER - 1);
    const int bl = idx >> 11;
    const int l = bl & (SEQLEN - 1);
    const float4 w4 = *reinterpret_cast<const float4*>(cw + (size_t)d * 4);
    const float wj[4] = {w4.x, w4.y, w4.z, w4.w};
    float acc = cb[d];
#pragma unroll
    for (int j = 0; j < 4; ++j) {
        const int ll = l - 3 + j;
        if (ll >= 0)
            acc += xr[(size_t)(bl - 3 + j) * D_INNER + d] * wj[j];
    }
    xc[idx] = acc * sigmoidf_(acc);
}

// ---------------------------------------------------------------------------
// Selective scan, chunked 3-pass.
// delta, xc, z: (B, L, D_INNER). dtbc: (B, L, 96) with dt[0:64], Bm[64:80], Cm[80:96].
// Chunk summaries: sum_delta[(c*B+b)*D + d], S[((c*B+b)*16+n)*D + d].
// ---------------------------------------------------------------------------
__global__ __launch_bounds__(256)
void scan1(const float* __restrict__ delta, const float* __restrict__ xc,
           const float* __restrict__ dtbc, const float* __restrict__ A_log,
           float* __restrict__ sum_delta, float* __restrict__ S_end) {
    const int d = blockIdx.x * 256 + threadIdx.x;
    const int b = blockIdx.y;
    const int c = blockIdx.z;
    __shared__ float bc[CH][32];
    for (int i = threadIdx.x; i < CH * 32; i += 256) {
        const int row = i >> 5, col = i & 31;
        bc[row][col] = dtbc[(size_t)(b * SEQLEN + c * CH + row) * NPROJ + DT_RANK + col];
    }
    __syncthreads();
    float A[16];
#pragma unroll
    for (int n = 0; n < 16; ++n) A[n] = -__expf(A_log[(size_t)d * 16 + n]);
    float s[16] = {0.f};
    float sd = 0.f;
    const size_t base = ((size_t)b * SEQLEN + (size_t)c * CH) * D_INNER + d;
    for (int li = 0; li < CH; ++li) {
        const float dl = delta[base + (size_t)li * D_INNER];
        const float xv = xc[base + (size_t)li * D_INNER];
        sd += dl;
        const float dx = dl * xv;
#pragma unroll
        for (int n = 0; n < 16; ++n) {
            const float a = __expf(dl * A[n]);
            s[n] = fmaf(s[n], a, dx * bc[li][n]);
        }
    }
    sum_delta[((size_t)c * BATCH + b) * D_INNER + d] = sd;
#pragma unroll
    for (int n = 0; n < 16; ++n)
        S_end[(((size_t)c * BATCH + b) * 16 + n) * D_INNER + d] = s[n];
}

// In-place: S[] holds chunk end-states on entry, chunk init-states on exit.
__global__ __launch_bounds__(256)
void scan2(const float* __restrict__ sum_delta, float* __restrict__ S,
           const float* __restrict__ A_log) {
    const int idx = blockIdx.x * 256 + threadIdx.x;  // b*D + d
    const int d = idx & (D_INNER - 1);
    const int b = idx >> 11;
    float A[16];
#pragma unroll
    for (int n = 0; n < 16; ++n) A[n] = -__expf(A_log[(size_t)d * 16 + n]);
    float carry[16] = {0.f};
    for (int c = 0; c < NCH; ++c) {
        const float sd = sum_delta[((size_t)c * BATCH + b) * D_INNER + d];
#pragma unroll
        for (int n = 0; n < 16; ++n) {
            const size_t o = (((size_t)c * BATCH + b) * 16 + n) * D_INNER + d;
            const float se = S[o];
            S[o] = carry[n];
            const float P = __expf(sd * A[n]);
            carry[n] = fmaf(carry[n], P, se);
        }
    }
}

__global__ __launch_bounds__(256)
void scan3(float* __restrict__ delta /* in: delta, out: gated y */,
           const float* __restrict__ xc, const float* __restrict__ z,
           const float* __restrict__ dtbc, const float* __restrict__ A_log,
           const float* __restrict__ S_init, const float* __restrict__ Dp) {
    const int d = blockIdx.x * 256 + threadIdx.x;
    const int b = blockIdx.y;
    const int c = blockIdx.z;
    __shared__ float bc[CH][32];
    for (int i = threadIdx.x; i < CH * 32; i += 256) {
        const int row = i >> 5, col = i & 31;
        bc[row][col] = dtbc[(size_t)(b * SEQLEN + c * CH + row) * NPROJ + DT_RANK + col];
    }
    __syncthreads();
    float A[16];
#pragma unroll
    for (int n = 0; n < 16; ++n) A[n] = -__expf(A_log[(size_t)d * 16 + n]);
    float s[16];
#pragma unroll
    for (int n = 0; n < 16; ++n)
        s[n] = S_init[(((size_t)c * BATCH + b) * 16 + n) * D_INNER + d];
    const float Dv = Dp[d];
    const size_t base = ((size_t)b * SEQLEN + (size_t)c * CH) * D_INNER + d;
    for (int li = 0; li < CH; ++li) {
        const size_t o = base + (size_t)li * D_INNER;
        const float dl = delta[o];
        const float xv = xc[o];
        const float dx = dl * xv;
        float y = 0.f;
#pragma unroll
        for (int n = 0; n < 16; ++n) {
            const float a = __expf(dl * A[n]);
            s[n] = fmaf(s[n], a, dx * bc[li][n]);
            y = fmaf(s[n], bc[li][16 + n], y);
        }
        const float zv = z[o];
        delta[o] = (y + Dv * xv) * (zv * sigmoidf_(zv));
    }
}

// ---------------------------------------------------------------------------
extern "C" void kernel_launch(void* const* d_in, const int* in_sizes, int n_in,
                              void* d_out, int out_size, void* d_ws, size_t ws_size,
                              hipStream_t stream) {
    const float* hidden   = (const float*)d_in[0];
    const float* W_in     = (const float*)d_in[1];
    const float* conv_w   = (const float*)d_in[2];
    const float* conv_b   = (const float*)d_in[3];
    const float* x_proj_w = (const float*)d_in[4];
    const float* dt_w     = (const float*)d_in[5];
    const float* dt_b     = (const float*)d_in[6];
    const float* A_log    = (const float*)d_in[7];
    const float* Dp       = (const float*)d_in[8];
    const float* W_out    = (const float*)d_in[9];
    float* out = (float*)d_out;

    // Workspace layout (floats), peak 212 MiB:
    float* ws   = (float*)d_ws;
    float* xbuf = ws;                                   // BL*D_INNER (pre-conv x; then delta; then y)
    float* zbuf = xbuf + (size_t)BL * D_INNER;          // BL*D_INNER
    float* xc   = zbuf + (size_t)BL * D_INNER;          // BL*D_INNER
    float* dtbc = xc + (size_t)BL * D_INNER;            // BL*NPROJ
    float* sumd = dtbc + (size_t)BL * NPROJ;            // NCH*BATCH*D_INNER
    float* Send = sumd + (size_t)NCH * BATCH * D_INNER; // NCH*BATCH*16*D_INNER (in-place S_init)

    const dim3 thr(256);

    // 1a) x = hidden @ W_in[even rows]^T  (row-stride trick: ldb = 2*D_MODEL)
    gemm_nt<0><<<dim3(D_INNER / 64, BL / 64), thr, 0, stream>>>(
        hidden, W_in, xbuf, BL, D_INNER, D_MODEL, D_MODEL, 2 * D_MODEL, D_INNER, nullptr);
    // 1b) z = hidden @ W_in[odd rows]^T
    gemm_nt<0><<<dim3(D_INNER / 64, BL / 64), thr, 0, stream>>>(
        hidden, W_in + D_MODEL, zbuf, BL, D_INNER, D_MODEL, D_MODEL, 2 * D_MODEL, D_INNER, nullptr);

    // 2) depthwise causal conv + bias + SiLU -> xc
    conv_silu_k<<<dim3(BL * D_INNER / 256), thr, 0, stream>>>(xbuf, conv_w, conv_b, xc);

    // 3) x_dbl = xc @ x_proj_w^T  (N=96, guarded)
    gemm_nt<2><<<dim3(2, BL / 64), thr, 0, stream>>>(
        xc, x_proj_w, dtbc, BL, NPROJ, D_INNER, D_INNER, D_INNER, NPROJ, nullptr);

    // 4) delta = softplus(dt @ dt_w^T + dt_b) -> reuse xbuf (pre-conv x is dead)
    gemm_nt<1><<<dim3(D_INNER / 64, BL / 64), thr, 0, stream>>>(
        dtbc, dt_w, xbuf, BL, D_INNER, DT_RANK, NPROJ, DT_RANK, D_INNER, dt_b);

    // 5-7) chunked selective scan (+ fused D*x skip and SiLU(z) gating in pass 3)
    scan1<<<dim3(D_INNER / 256, BATCH, NCH), thr, 0, stream>>>(
        xbuf, xc, dtbc, A_log, sumd, Send);
    scan2<<<dim3(BATCH * D_INNER / 256), thr, 0, stream>>>(sumd, Send, A_log);
    scan3<<<dim3(D_INNER / 256, BATCH, NCH), thr, 0, stream>>>(
        xbuf, xc, zbuf, dtbc, A_log, Send, Dp);

    // 8) out = y2 @ W_out^T
    gemm_nt<0><<<dim3(D_MODEL / 64, BL / 64), thr, 0, stream>>>(
        xbuf, W_out, out, BL, D_MODEL, D_INNER, D_INNER, D_INNER, D_MODEL, nullptr);
}

// Round 4
// 866.073 us; speedup vs baseline: 2.1195x; 2.1195x over previous
//
#include <hip/hip_runtime.h>
#include <hip/hip_bf16.h>

#define D_MODEL 1024
#define D_INNER 2048
#define D_STATE 16
#define DT_RANK 64
#define BATCH 2
#define SEQLEN 4096
#define BL (BATCH * SEQLEN)           // 8192 rows (b,l)
#define NPROJ (DT_RANK + 2 * D_STATE) // 96
#define CH 64                         // scan chunk length
#define NCH (SEQLEN / CH)             // 64 chunks

typedef __attribute__((ext_vector_type(8))) short bf16x8;
typedef __attribute__((ext_vector_type(4))) float f32x4;
struct S4 { short x, y, z, w; };

__device__ __forceinline__ float sigmoidf_(float v) {
    return 1.0f / (1.0f + __expf(-v));
}

__device__ __forceinline__ unsigned short bf16_rne(float f) {
    unsigned u = __float_as_uint(f);
    unsigned r = u + 0x7FFFu + ((u >> 16) & 1u);
    return (unsigned short)(r >> 16);
}

// ---------------------------------------------------------------------------
// Split fp32 -> bf16 hi + bf16 lo (lo = rne(x - hi)); rel err ~2^-17.
// ---------------------------------------------------------------------------
__global__ __launch_bounds__(256)
void cvt_split(const float* __restrict__ in, short* __restrict__ hi,
               short* __restrict__ lo, int n4) {
    const int i = blockIdx.x * 256 + threadIdx.x;
    if (i >= n4) return;
    const float4 v = reinterpret_cast<const float4*>(in)[i];
    const float f[4] = {v.x, v.y, v.z, v.w};
    S4 h, l;
    short hb[4], lb[4];
#pragma unroll
    for (int j = 0; j < 4; ++j) {
        const unsigned short hh = bf16_rne(f[j]);
        const float hf = __uint_as_float((unsigned)hh << 16);
        hb[j] = (short)hh;
        lb[j] = (short)bf16_rne(f[j] - hf);
    }
    h.x = hb[0]; h.y = hb[1]; h.z = hb[2]; h.w = hb[3];
    l.x = lb[0]; l.y = lb[1]; l.z = lb[2]; l.w = lb[3];
    *reinterpret_cast<S4*>(hi + (size_t)i * 4) = h;
    *reinterpret_cast<S4*>(lo + (size_t)i * 4) = l;
}

// ---------------------------------------------------------------------------
// bf16x3 split-precision MFMA NT GEMM: C[M,N] = (Ahi+Alo)[M,K] * (Bhi+Blo)[N,K]^T
// (drops lo*lo term). 128x128 tile, BK=32, 4 waves; wave w stages stream w via
// global_load_lds width 16; each wave computes a 64x64 quadrant as 4x4 frags
// of v_mfma_f32_16x16x32_bf16 (3 MFMA per frag pair).
// Requires M%128==0, N%128==0, K%32==0.
// ---------------------------------------------------------------------------
__global__ __launch_bounds__(256)
void gemm_bf16x3(const short* __restrict__ Ahi, const short* __restrict__ Alo,
                 const short* __restrict__ Bhi, const short* __restrict__ Blo,
                 float* __restrict__ C, int K, int lda, int ldb, int ldc) {
    __shared__ short sA[2][128][32];  // [hi/lo][row][k]  8 KB each
    __shared__ short sB[2][128][32];
    const int t = threadIdx.x;
    const int w = t >> 6, l = t & 63;
    const int m0 = blockIdx.y * 128, n0 = blockIdx.x * 128;
    const int wr = w >> 1, wc = w & 1;

    // staging assignment: wave 0->Ahi, 1->Alo, 2->Bhi, 3->Blo
    const short* gsrc;
    short* sdst;
    int ld, tile0;
    if (w == 0)      { gsrc = Ahi; sdst = &sA[0][0][0]; tile0 = m0; ld = lda; }
    else if (w == 1) { gsrc = Alo; sdst = &sA[1][0][0]; tile0 = m0; ld = lda; }
    else if (w == 2) { gsrc = Bhi; sdst = &sB[0][0][0]; tile0 = n0; ld = ldb; }
    else             { gsrc = Blo; sdst = &sB[1][0][0]; tile0 = n0; ld = ldb; }
    // call i covers rows 16i..16i+15: lane l -> row 16i+(l>>2), k-elems (l&3)*8
    const size_t grow = (size_t)(tile0 + (l >> 2)) * ld + ((l & 3) << 3);

    f32x4 acc[4][4] = {};
    const int frow = l & 15;          // fragment row (A) / col-row (B)
    const int kb = (l >> 4) << 3;     // fragment k element offset

    for (int k0 = 0; k0 < K; k0 += 32) {
        __syncthreads();  // previous tile's ds_reads complete (full drain at barrier)
#pragma unroll
        for (int i = 0; i < 8; ++i) {
            const short* g = gsrc + grow + (size_t)(i << 4) * ld + k0;
            __builtin_amdgcn_global_load_lds(
                (const __attribute__((address_space(1))) void*)g,
                (__attribute__((address_space(3))) void*)(sdst + (i << 9)),
                16, 0, 0);
        }
        __syncthreads();  // compiler drains vmcnt(0) before s_barrier -> staged data visible

        bf16x8 a[2][4], b[2][4];
#pragma unroll
        for (int f = 0; f < 4; ++f) {
            a[0][f] = *reinterpret_cast<const bf16x8*>(&sA[0][wr * 64 + f * 16 + frow][kb]);
            a[1][f] = *reinterpret_cast<const bf16x8*>(&sA[1][wr * 64 + f * 16 + frow][kb]);
            b[0][f] = *reinterpret_cast<const bf16x8*>(&sB[0][wc * 64 + f * 16 + frow][kb]);
            b[1][f] = *reinterpret_cast<const bf16x8*>(&sB[1][wc * 64 + f * 16 + frow][kb]);
        }
#pragma unroll
        for (int fi = 0; fi < 4; ++fi)
#pragma unroll
            for (int fj = 0; fj < 4; ++fj) {
                acc[fi][fj] = __builtin_amdgcn_mfma_f32_16x16x32_bf16(
                    a[0][fi], b[0][fj], acc[fi][fj], 0, 0, 0);
                acc[fi][fj] = __builtin_amdgcn_mfma_f32_16x16x32_bf16(
                    a[1][fi], b[0][fj], acc[fi][fj], 0, 0, 0);
                acc[fi][fj] = __builtin_amdgcn_mfma_f32_16x16x32_bf16(
                    a[0][fi], b[1][fj], acc[fi][fj], 0, 0, 0);
            }
    }

    // C/D layout (m89-verified): col = lane&15, row = (lane>>4)*4 + reg
    const int crow = (l >> 4) << 2;
    const int ccol = l & 15;
#pragma unroll
    for (int fi = 0; fi < 4; ++fi)
#pragma unroll
        for (int fj = 0; fj < 4; ++fj)
#pragma unroll
            for (int r = 0; r < 4; ++r)
                C[(size_t)(m0 + wr * 64 + fi * 16 + crow + r) * ldc
                  + (n0 + wc * 64 + fj * 16 + ccol)] = acc[fi][fj][r];
}

// ---------------------------------------------------------------------------
// fp32 NT GEMM (small GEMMs only): C = A * B^T.
// EPI: 1 = softplus(v + bias[n]), 2 = plain store with n<N guard
// ---------------------------------------------------------------------------
template <int EPI>
__global__ __launch_bounds__(256)
void gemm_nt(const float* __restrict__ A, const float* __restrict__ B,
             float* __restrict__ C, int M, int N, int K,
             int lda, int ldb, int ldc, const float* __restrict__ bias) {
    constexpr int BM = 64, BN = 64, BK = 16, PAD = 4;
    __shared__ float As[BK][BM + PAD];
    __shared__ float Bs[BK][BN + PAD];
    const int t = threadIdx.x;
    const int tx = t & 15, ty = t >> 4;
    const int m0 = blockIdx.y * BM, n0 = blockIdx.x * BN;
    const int lrow = t >> 2;
    const int lcol = (t & 3) * 4;

    float acc[4][4] = {{0.f}};

    for (int k0 = 0; k0 < K; k0 += BK) {
        float4 av = *reinterpret_cast<const float4*>(
            A + (size_t)(m0 + lrow) * lda + k0 + lcol);
        float4 bv;
        if (EPI != 2 || n0 + lrow < N)
            bv = *reinterpret_cast<const float4*>(
                B + (size_t)(n0 + lrow) * ldb + k0 + lcol);
        else
            bv = make_float4(0.f, 0.f, 0.f, 0.f);
        __syncthreads();
        As[lcol + 0][lrow] = av.x; As[lcol + 1][lrow] = av.y;
        As[lcol + 2][lrow] = av.z; As[lcol + 3][lrow] = av.w;
        Bs[lcol + 0][lrow] = bv.x; Bs[lcol + 1][lrow] = bv.y;
        Bs[lcol + 2][lrow] = bv.z; Bs[lcol + 3][lrow] = bv.w;
        __syncthreads();
#pragma unroll
        for (int k = 0; k < BK; ++k) {
            float4 a = *reinterpret_cast<const float4*>(&As[k][ty * 4]);
            float4 b = *reinterpret_cast<const float4*>(&Bs[k][tx * 4]);
            float ar[4] = {a.x, a.y, a.z, a.w};
            float br[4] = {b.x, b.y, b.z, b.w};
#pragma unroll
            for (int i = 0; i < 4; ++i)
#pragma unroll
                for (int j = 0; j < 4; ++j)
                    acc[i][j] = fmaf(ar[i], br[j], acc[i][j]);
        }
    }

#pragma unroll
    for (int i = 0; i < 4; ++i) {
        const int m = m0 + ty * 4 + i;
#pragma unroll
        for (int j = 0; j < 4; ++j) {
            const int n = n0 + tx * 4 + j;
            if (EPI == 2 && n >= N) continue;
            float v = acc[i][j];
            if (EPI == 1) {
                v += bias[n];
                v = fmaxf(v, 0.f) + log1pf(__expf(-fabsf(v)));  // stable softplus
            }
            C[(size_t)m * ldc + n] = v;
        }
    }
}

// ---------------------------------------------------------------------------
// Depthwise causal conv (D_CONV=4) + bias + SiLU. (B, L, D_INNER) layout.
// ---------------------------------------------------------------------------
__global__ __launch_bounds__(256)
void conv_silu_k(const float* __restrict__ xr, const float* __restrict__ cw,
                 const float* __restrict__ cb, float* __restrict__ xc) {
    const int idx = blockIdx.x * 256 + threadIdx.x;
    const int d = idx & (D_INNER - 1);
    const int bl = idx >> 11;
    const int l = bl & (SEQLEN - 1);
    const float4 w4 = *reinterpret_cast<const float4*>(cw + (size_t)d * 4);
    const float wj[4] = {w4.x, w4.y, w4.z, w4.w};
    float acc = cb[d];
#pragma unroll
    for (int j = 0; j < 4; ++j) {
        const int ll = l - 3 + j;
        if (ll >= 0)
            acc += xr[(size_t)(bl - 3 + j) * D_INNER + d] * wj[j];
    }
    xc[idx] = acc * sigmoidf_(acc);
}

// ---------------------------------------------------------------------------
// Selective scan, chunked 3-pass (as round 3, verified).
// ---------------------------------------------------------------------------
__global__ __launch_bounds__(256)
void scan1(const float* __restrict__ delta, const float* __restrict__ xc,
           const float* __restrict__ dtbc, const float* __restrict__ A_log,
           float* __restrict__ sum_delta, float* __restrict__ S_end) {
    const int d = blockIdx.x * 256 + threadIdx.x;
    const int b = blockIdx.y;
    const int c = blockIdx.z;
    __shared__ float bc[CH][32];
    for (int i = threadIdx.x; i < CH * 32; i += 256) {
        const int row = i >> 5, col = i & 31;
        bc[row][col] = dtbc[(size_t)(b * SEQLEN + c * CH + row) * NPROJ + DT_RANK + col];
    }
    __syncthreads();
    float A[16];
#pragma unroll
    for (int n = 0; n < 16; ++n) A[n] = -__expf(A_log[(size_t)d * 16 + n]);
    float s[16] = {0.f};
    float sd = 0.f;
    const size_t base = ((size_t)b * SEQLEN + (size_t)c * CH) * D_INNER + d;
    for (int li = 0; li < CH; ++li) {
        const float dl = delta[base + (size_t)li * D_INNER];
        const float xv = xc[base + (size_t)li * D_INNER];
        sd += dl;
        const float dx = dl * xv;
#pragma unroll
        for (int n = 0; n < 16; ++n) {
            const float a = __expf(dl * A[n]);
            s[n] = fmaf(s[n], a, dx * bc[li][n]);
        }
    }
    sum_delta[((size_t)c * BATCH + b) * D_INNER + d] = sd;
#pragma unroll
    for (int n = 0; n < 16; ++n)
        S_end[(((size_t)c * BATCH + b) * 16 + n) * D_INNER + d] = s[n];
}

__global__ __launch_bounds__(256)
void scan2(const float* __restrict__ sum_delta, float* __restrict__ S,
           const float* __restrict__ A_log) {
    const int idx = blockIdx.x * 256 + threadIdx.x;
    const int d = idx & (D_INNER - 1);
    const int b = idx >> 11;
    float A[16];
#pragma unroll
    for (int n = 0; n < 16; ++n) A[n] = -__expf(A_log[(size_t)d * 16 + n]);
    float carry[16] = {0.f};
    for (int c = 0; c < NCH; ++c) {
        const float sd = sum_delta[((size_t)c * BATCH + b) * D_INNER + d];
#pragma unroll
        for (int n = 0; n < 16; ++n) {
            const size_t o = (((size_t)c * BATCH + b) * 16 + n) * D_INNER + d;
            const float se = S[o];
            S[o] = carry[n];
            const float P = __expf(sd * A[n]);
            carry[n] = fmaf(carry[n], P, se);
        }
    }
}

__global__ __launch_bounds__(256)
void scan3(float* __restrict__ delta /* in: delta, out: gated y */,
           const float* __restrict__ xc, const float* __restrict__ z,
           const float* __restrict__ dtbc, const float* __restrict__ A_log,
           const float* __restrict__ S_init, const float* __restrict__ Dp) {
    const int d = blockIdx.x * 256 + threadIdx.x;
    const int b = blockIdx.y;
    const int c = blockIdx.z;
    __shared__ float bc[CH][32];
    for (int i = threadIdx.x; i < CH * 32; i += 256) {
        const int row = i >> 5, col = i & 31;
        bc[row][col] = dtbc[(size_t)(b * SEQLEN + c * CH + row) * NPROJ + DT_RANK + col];
    }
    __syncthreads();
    float A[16];
#pragma unroll
    for (int n = 0; n < 16; ++n) A[n] = -__expf(A_log[(size_t)d * 16 + n]);
    float s[16];
#pragma unroll
    for (int n = 0; n < 16; ++n)
        s[n] = S_init[(((size_t)c * BATCH + b) * 16 + n) * D_INNER + d];
    const float Dv = Dp[d];
    const size_t base = ((size_t)b * SEQLEN + (size_t)c * CH) * D_INNER + d;
    for (int li = 0; li < CH; ++li) {
        const size_t o = base + (size_t)li * D_INNER;
        const float dl = delta[o];
        const float xv = xc[o];
        const float dx = dl * xv;
        float y = 0.f;
#pragma unroll
        for (int n = 0; n < 16; ++n) {
            const float a = __expf(dl * A[n]);
            s[n] = fmaf(s[n], a, dx * bc[li][n]);
            y = fmaf(s[n], bc[li][16 + n], y);
        }
        const float zv = z[o];
        delta[o] = (y + Dv * xv) * (zv * sigmoidf_(zv));
    }
}

// ---------------------------------------------------------------------------
extern "C" void kernel_launch(void* const* d_in, const int* in_sizes, int n_in,
                              void* d_out, int out_size, void* d_ws, size_t ws_size,
                              hipStream_t stream) {
    const float* hidden   = (const float*)d_in[0];
    const float* W_in     = (const float*)d_in[1];
    const float* conv_w   = (const float*)d_in[2];
    const float* conv_b   = (const float*)d_in[3];
    const float* x_proj_w = (const float*)d_in[4];
    const float* dt_w     = (const float*)d_in[5];
    const float* dt_b     = (const float*)d_in[6];
    const float* A_log    = (const float*)d_in[7];
    const float* Dp       = (const float*)d_in[8];
    const float* W_out    = (const float*)d_in[9];
    float* out = (float*)d_out;

    // Workspace layout (floats), peak 222 MB (proven available in round 3):
    float* ws   = (float*)d_ws;
    float* xbuf = ws;                                   // BL*D_INNER (x; delta; y)
    float* zbuf = xbuf + (size_t)BL * D_INNER;          // BL*D_INNER (z; later y hi/lo bf16)
    float* xc   = zbuf + (size_t)BL * D_INNER;          // BL*D_INNER (bf16 stage; xc; W_out hi/lo)
    float* dtbc = xc + (size_t)BL * D_INNER;            // BL*NPROJ
    float* sumd = dtbc + (size_t)BL * NPROJ;            // NCH*BATCH*D_INNER
    float* Send = sumd + (size_t)NCH * BATCH * D_INNER; // NCH*BATCH*16*D_INNER

    // bf16 split buffers for GEMM1 live in the (not yet written) xc region:
    short* hxhi  = (short*)xc;                             // BL*D_MODEL
    short* hxlo  = hxhi + (size_t)BL * D_MODEL;
    short* winhi = hxlo + (size_t)BL * D_MODEL;            // (2*D_INNER)*D_MODEL
    short* winlo = winhi + (size_t)2 * D_INNER * D_MODEL;  // ends at 25.2M shorts < 33.5M cap

    const dim3 thr(256);

    // 0) split-convert hidden and W_in to bf16 hi/lo
    cvt_split<<<dim3(BL * D_MODEL / 4 / 256), thr, 0, stream>>>(hidden, hxhi, hxlo, BL * D_MODEL / 4);
    cvt_split<<<dim3(2 * D_INNER * D_MODEL / 4 / 256), thr, 0, stream>>>(W_in, winhi, winlo, 2 * D_INNER * D_MODEL / 4);

    // 1a) x = hidden @ W_in[even rows]^T   (ldb = 2*D_MODEL row-stride trick)
    gemm_bf16x3<<<dim3(D_INNER / 128, BL / 128), thr, 0, stream>>>(
        hxhi, hxlo, winhi, winlo, xbuf, D_MODEL, D_MODEL, 2 * D_MODEL, D_INNER);
    // 1b) z = hidden @ W_in[odd rows]^T
    gemm_bf16x3<<<dim3(D_INNER / 128, BL / 128), thr, 0, stream>>>(
        hxhi, hxlo, winhi + D_MODEL, winlo + D_MODEL, zbuf, D_MODEL, D_MODEL, 2 * D_MODEL, D_INNER);

    // 2) depthwise causal conv + bias + SiLU -> xc (overwrites bf16 stage area)
    conv_silu_k<<<dim3(BL * D_INNER / 256), thr, 0, stream>>>(xbuf, conv_w, conv_b, xc);

    // 3) x_dbl = xc @ x_proj_w^T  (N=96, fp32, guarded)
    gemm_nt<2><<<dim3(2, BL / 64), thr, 0, stream>>>(
        xc, x_proj_w, dtbc, BL, NPROJ, D_INNER, D_INNER, D_INNER, NPROJ, nullptr);

    // 4) delta = softplus(dt @ dt_w^T + dt_b) -> xbuf (pre-conv x is dead)
    gemm_nt<1><<<dim3(D_INNER / 64, BL / 64), thr, 0, stream>>>(
        dtbc, dt_w, xbuf, BL, D_INNER, DT_RANK, NPROJ, DT_RANK, D_INNER, dt_b);

    // 5-7) chunked selective scan; scan3 writes gated y into xbuf
    scan1<<<dim3(D_INNER / 256, BATCH, NCH), thr, 0, stream>>>(
        xbuf, xc, dtbc, A_log, sumd, Send);
    scan2<<<dim3(BATCH * D_INNER / 256), thr, 0, stream>>>(sumd, Send, A_log);
    scan3<<<dim3(D_INNER / 256, BATCH, NCH), thr, 0, stream>>>(
        xbuf, xc, zbuf, dtbc, A_log, Send, Dp);

    // 8) split-convert y (xbuf) -> zbuf region, W_out -> xc region (both dead now)
    short* yhi  = (short*)zbuf;                       // BL*D_INNER shorts
    short* ylo  = yhi + (size_t)BL * D_INNER;         // fits zbuf exactly
    short* wohi = (short*)xc;                         // D_MODEL*D_INNER
    short* wolo = wohi + (size_t)D_MODEL * D_INNER;
    cvt_split<<<dim3(BL * D_INNER / 4 / 256), thr, 0, stream>>>(xbuf, yhi, ylo, BL * D_INNER / 4);
    cvt_split<<<dim3(D_MODEL * D_INNER / 4 / 256), thr, 0, stream>>>(W_out, wohi, wolo, D_MODEL * D_INNER / 4);

    // 9) out = y2 @ W_out^T
    gemm_bf16x3<<<dim3(D_MODEL / 128, BL / 128), thr, 0, stream>>>(
        yhi, ylo, wohi, wolo, out, D_INNER, D_INNER, D_INNER, D_MODEL);
}

// Round 5
// 790.170 us; speedup vs baseline: 2.3231x; 1.0961x over previous
//
#include <hip/hip_runtime.h>
#include <hip/hip_bf16.h>

#define D_MODEL 1024
#define D_INNER 2048
#define D_STATE 16
#define DT_RANK 64
#define BATCH 2
#define SEQLEN 4096
#define BL (BATCH * SEQLEN)           // 8192 rows (b,l)
#define NPROJ (DT_RANK + 2 * D_STATE) // 96
#define CH 64                         // scan chunk length
#define NCH (SEQLEN / CH)             // 64 chunks

typedef __attribute__((ext_vector_type(8))) short bf16x8;
typedef __attribute__((ext_vector_type(4))) float f32x4;
struct S4 { short x, y, z, w; };

__device__ __forceinline__ float sigmoidf_(float v) {
    return 1.0f / (1.0f + __expf(-v));
}

__device__ __forceinline__ unsigned short bf16_rne(float f) {
    unsigned u = __float_as_uint(f);
    unsigned r = u + 0x7FFFu + ((u >> 16) & 1u);
    return (unsigned short)(r >> 16);
}

__device__ __forceinline__ float bf2f(short s) {
    return __uint_as_float(((unsigned)(unsigned short)s) << 16);
}

// ---------------------------------------------------------------------------
// Split fp32 -> bf16 hi + bf16 lo (lo = rne(x - hi)); rel err ~2^-17.
// ---------------------------------------------------------------------------
__global__ __launch_bounds__(256)
void cvt_split(const float* __restrict__ in, short* __restrict__ hi,
               short* __restrict__ lo, int n4) {
    const int i = blockIdx.x * 256 + threadIdx.x;
    if (i >= n4) return;
    const float4 v = reinterpret_cast<const float4*>(in)[i];
    const float f[4] = {v.x, v.y, v.z, v.w};
    S4 h, l;
    short hb[4], lb[4];
#pragma unroll
    for (int j = 0; j < 4; ++j) {
        const unsigned short hh = bf16_rne(f[j]);
        const float hf = __uint_as_float((unsigned)hh << 16);
        hb[j] = (short)hh;
        lb[j] = (short)bf16_rne(f[j] - hf);
    }
    h.x = hb[0]; h.y = hb[1]; h.z = hb[2]; h.w = hb[3];
    l.x = lb[0]; l.y = lb[1]; l.z = lb[2]; l.w = lb[3];
    *reinterpret_cast<S4*>(hi + (size_t)i * 4) = h;
    *reinterpret_cast<S4*>(lo + (size_t)i * 4) = l;
}

// ---------------------------------------------------------------------------
// bf16x3 split-precision MFMA NT GEMM (verified round 4). 128x128 tile, BK=32,
// 4 waves (one stages each of Ahi/Alo/Bhi/Blo via global_load_lds width 16).
// + XCD-aware block swizzle (T1) for L2 locality.
// Requires M%128==0, N%128==0, K%32==0, grid%8==0.
// ---------------------------------------------------------------------------
__global__ __launch_bounds__(256)
void gemm_bf16x3(const short* __restrict__ Ahi, const short* __restrict__ Alo,
                 const short* __restrict__ Bhi, const short* __restrict__ Blo,
                 float* __restrict__ C, int K, int lda, int ldb, int ldc) {
    __shared__ short sA[2][128][32];  // [hi/lo][row][k]
    __shared__ short sB[2][128][32];
    const int t = threadIdx.x;
    const int w = t >> 6, l = t & 63;

    // XCD swizzle: contiguous chunk of blocks per XCD (grid % 8 == 0 here)
    const int nwg = gridDim.x * gridDim.y;
    int bid = blockIdx.y * gridDim.x + blockIdx.x;
    if ((nwg & 7) == 0) bid = (bid & 7) * (nwg >> 3) + (bid >> 3);
    const int m0 = (bid / gridDim.x) * 128, n0 = (bid % gridDim.x) * 128;
    const int wr = w >> 1, wc = w & 1;

    // staging assignment: wave 0->Ahi, 1->Alo, 2->Bhi, 3->Blo
    const short* gsrc;
    short* sdst;
    int ld, tile0;
    if (w == 0)      { gsrc = Ahi; sdst = &sA[0][0][0]; tile0 = m0; ld = lda; }
    else if (w == 1) { gsrc = Alo; sdst = &sA[1][0][0]; tile0 = m0; ld = lda; }
    else if (w == 2) { gsrc = Bhi; sdst = &sB[0][0][0]; tile0 = n0; ld = ldb; }
    else             { gsrc = Blo; sdst = &sB[1][0][0]; tile0 = n0; ld = ldb; }
    const size_t grow = (size_t)(tile0 + (l >> 2)) * ld + ((l & 3) << 3);

    f32x4 acc[4][4] = {};
    const int frow = l & 15;
    const int kb = (l >> 4) << 3;

    for (int k0 = 0; k0 < K; k0 += 32) {
        __syncthreads();
#pragma unroll
        for (int i = 0; i < 8; ++i) {
            const short* g = gsrc + grow + (size_t)(i << 4) * ld + k0;
            __builtin_amdgcn_global_load_lds(
                (const __attribute__((address_space(1))) void*)g,
                (__attribute__((address_space(3))) void*)(sdst + (i << 9)),
                16, 0, 0);
        }
        __syncthreads();

        bf16x8 a[2][4], b[2][4];
#pragma unroll
        for (int f = 0; f < 4; ++f) {
            a[0][f] = *reinterpret_cast<const bf16x8*>(&sA[0][wr * 64 + f * 16 + frow][kb]);
            a[1][f] = *reinterpret_cast<const bf16x8*>(&sA[1][wr * 64 + f * 16 + frow][kb]);
            b[0][f] = *reinterpret_cast<const bf16x8*>(&sB[0][wc * 64 + f * 16 + frow][kb]);
            b[1][f] = *reinterpret_cast<const bf16x8*>(&sB[1][wc * 64 + f * 16 + frow][kb]);
        }
#pragma unroll
        for (int fi = 0; fi < 4; ++fi)
#pragma unroll
            for (int fj = 0; fj < 4; ++fj) {
                acc[fi][fj] = __builtin_amdgcn_mfma_f32_16x16x32_bf16(
                    a[0][fi], b[0][fj], acc[fi][fj], 0, 0, 0);
                acc[fi][fj] = __builtin_amdgcn_mfma_f32_16x16x32_bf16(
                    a[1][fi], b[0][fj], acc[fi][fj], 0, 0, 0);
                acc[fi][fj] = __builtin_amdgcn_mfma_f32_16x16x32_bf16(
                    a[0][fi], b[1][fj], acc[fi][fj], 0, 0, 0);
            }
    }

    // C/D layout (m89-verified): col = lane&15, row = (lane>>4)*4 + reg
    const int crow = (l >> 4) << 2;
    const int ccol = l & 15;
#pragma unroll
    for (int fi = 0; fi < 4; ++fi)
#pragma unroll
        for (int fj = 0; fj < 4; ++fj)
#pragma unroll
            for (int r = 0; r < 4; ++r)
                C[(size_t)(m0 + wr * 64 + fi * 16 + crow + r) * ldc
                  + (n0 + wc * 64 + fj * 16 + ccol)] = acc[fi][fj][r];
}

// ---------------------------------------------------------------------------
// Tall-skinny bf16x3 MFMA GEMM for x_proj: C[BL x 96] = X[BL x 2048]*W[96 x 2048]^T.
// No LDS: fragments loaded directly from global (W is 768 KB -> L2 resident).
// Block = 32 rows, 4 waves; wave w: row-frag (w>>1), col-frags (w&1)*3..+2.
// ---------------------------------------------------------------------------
__global__ __launch_bounds__(256)
void gemm96(const short* __restrict__ Xhi, const short* __restrict__ Xlo,
            const short* __restrict__ Whi, const short* __restrict__ Wlo,
            float* __restrict__ C) {
    const int t = threadIdx.x;
    const int w = t >> 6, l = t & 63;
    const int m0 = blockIdx.x * 32;
    const int rfrag = (w >> 1) * 16;     // row-frag base within tile
    const int cbase = (w & 1) * 48;      // col base (3 frags of 16)
    const int lrow = l & 15;
    const int koff0 = (l >> 4) << 3;     // 0,8,16,24
    f32x4 acc[3] = {};
    const size_t arow = (size_t)(m0 + rfrag + lrow) * D_INNER;
#pragma unroll 2
    for (int k0 = 0; k0 < D_INNER; k0 += 32) {
        const int ko = k0 + koff0;
        const bf16x8 ah = *reinterpret_cast<const bf16x8*>(Xhi + arow + ko);
        const bf16x8 al = *reinterpret_cast<const bf16x8*>(Xlo + arow + ko);
#pragma unroll
        for (int jj = 0; jj < 3; ++jj) {
            const size_t brow = (size_t)(cbase + jj * 16 + lrow) * D_INNER + ko;
            const bf16x8 bh = *reinterpret_cast<const bf16x8*>(Whi + brow);
            const bf16x8 bl = *reinterpret_cast<const bf16x8*>(Wlo + brow);
            acc[jj] = __builtin_amdgcn_mfma_f32_16x16x32_bf16(ah, bh, acc[jj], 0, 0, 0);
            acc[jj] = __builtin_amdgcn_mfma_f32_16x16x32_bf16(al, bh, acc[jj], 0, 0, 0);
            acc[jj] = __builtin_amdgcn_mfma_f32_16x16x32_bf16(ah, bl, acc[jj], 0, 0, 0);
        }
    }
    const int crow = (l >> 4) << 2;
#pragma unroll
    for (int jj = 0; jj < 3; ++jj)
#pragma unroll
        for (int r = 0; r < 4; ++r)
            C[(size_t)(m0 + rfrag + crow + r) * NPROJ + cbase + jj * 16 + lrow] = acc[jj][r];
}

// ---------------------------------------------------------------------------
// fp32 NT GEMM (GEMM4 only: K=64). EPI 1 = softplus(v + bias[n]).
// ---------------------------------------------------------------------------
template <int EPI>
__global__ __launch_bounds__(256)
void gemm_nt(const float* __restrict__ A, const float* __restrict__ B,
             float* __restrict__ C, int M, int N, int K,
             int lda, int ldb, int ldc, const float* __restrict__ bias) {
    constexpr int BM = 64, BN = 64, BK = 16, PAD = 4;
    __shared__ float As[BK][BM + PAD];
    __shared__ float Bs[BK][BN + PAD];
    const int t = threadIdx.x;
    const int tx = t & 15, ty = t >> 4;
    const int m0 = blockIdx.y * BM, n0 = blockIdx.x * BN;
    const int lrow = t >> 2;
    const int lcol = (t & 3) * 4;

    float acc[4][4] = {{0.f}};

    for (int k0 = 0; k0 < K; k0 += BK) {
        float4 av = *reinterpret_cast<const float4*>(
            A + (size_t)(m0 + lrow) * lda + k0 + lcol);
        float4 bv = *reinterpret_cast<const float4*>(
            B + (size_t)(n0 + lrow) * ldb + k0 + lcol);
        __syncthreads();
        As[lcol + 0][lrow] = av.x; As[lcol + 1][lrow] = av.y;
        As[lcol + 2][lrow] = av.z; As[lcol + 3][lrow] = av.w;
        Bs[lcol + 0][lrow] = bv.x; Bs[lcol + 1][lrow] = bv.y;
        Bs[lcol + 2][lrow] = bv.z; Bs[lcol + 3][lrow] = bv.w;
        __syncthreads();
#pragma unroll
        for (int k = 0; k < BK; ++k) {
            float4 a = *reinterpret_cast<const float4*>(&As[k][ty * 4]);
            float4 b = *reinterpret_cast<const float4*>(&Bs[k][tx * 4]);
            float ar[4] = {a.x, a.y, a.z, a.w};
            float br[4] = {b.x, b.y, b.z, b.w};
#pragma unroll
            for (int i = 0; i < 4; ++i)
#pragma unroll
                for (int j = 0; j < 4; ++j)
                    acc[i][j] = fmaf(ar[i], br[j], acc[i][j]);
        }
    }

#pragma unroll
    for (int i = 0; i < 4; ++i) {
        const int m = m0 + ty * 4 + i;
#pragma unroll
        for (int j = 0; j < 4; ++j) {
            const int n = n0 + tx * 4 + j;
            float v = acc[i][j];
            if (EPI == 1) {
                v += bias[n];
                v = fmaxf(v, 0.f) + log1pf(__expf(-fabsf(v)));  // stable softplus
            }
            C[(size_t)m * ldc + n] = v;
        }
    }
}

// ---------------------------------------------------------------------------
// Depthwise causal conv (D_CONV=4) + bias + SiLU -> bf16 hi/lo split output.
// ---------------------------------------------------------------------------
__global__ __launch_bounds__(256)
void conv_silu_k(const float* __restrict__ xr, const float* __restrict__ cw,
                 const float* __restrict__ cb, short* __restrict__ xchi,
                 short* __restrict__ xclo) {
    const int idx = blockIdx.x * 256 + threadIdx.x;
    const int d = idx & (D_INNER - 1);
    const int bl = idx >> 11;
    const int l = bl & (SEQLEN - 1);
    const float4 w4 = *reinterpret_cast<const float4*>(cw + (size_t)d * 4);
    const float wj[4] = {w4.x, w4.y, w4.z, w4.w};
    float acc = cb[d];
#pragma unroll
    for (int j = 0; j < 4; ++j) {
        const int ll = l - 3 + j;
        if (ll >= 0)
            acc += xr[(size_t)(bl - 3 + j) * D_INNER + d] * wj[j];
    }
    const float v = acc * sigmoidf_(acc);
    const unsigned short hh = bf16_rne(v);
    xchi[idx] = (short)hh;
    xclo[idx] = (short)bf16_rne(v - __uint_as_float((unsigned)hh << 16));
}

// ---------------------------------------------------------------------------
// Selective scan, chunked 3-pass. x reconstructed from bf16 hi/lo (err 2^-17).
// ---------------------------------------------------------------------------
__global__ __launch_bounds__(256)
void scan1(const float* __restrict__ delta, const short* __restrict__ xchi,
           const short* __restrict__ xclo, const float* __restrict__ dtbc,
           const float* __restrict__ A_log, float* __restrict__ sum_delta,
           float* __restrict__ S_end) {
    const int d = blockIdx.x * 256 + threadIdx.x;
    const int b = blockIdx.y;
    const int c = blockIdx.z;
    __shared__ float bc[CH][32];
    for (int i = threadIdx.x; i < CH * 32; i += 256) {
        const int row = i >> 5, col = i & 31;
        bc[row][col] = dtbc[(size_t)(b * SEQLEN + c * CH + row) * NPROJ + DT_RANK + col];
    }
    __syncthreads();
    float A[16];
#pragma unroll
    for (int n = 0; n < 16; ++n) A[n] = -__expf(A_log[(size_t)d * 16 + n]);
    float s[16] = {0.f};
    float sd = 0.f;
    const size_t base = ((size_t)b * SEQLEN + (size_t)c * CH) * D_INNER + d;
    for (int li = 0; li < CH; ++li) {
        const size_t o = base + (size_t)li * D_INNER;
        const float dl = delta[o];
        const float xv = bf2f(xchi[o]) + bf2f(xclo[o]);
        sd += dl;
        const float dx = dl * xv;
#pragma unroll
        for (int n = 0; n < 16; ++n) {
            const float a = __expf(dl * A[n]);
            s[n] = fmaf(s[n], a, dx * bc[li][n]);
        }
    }
    sum_delta[((size_t)c * BATCH + b) * D_INNER + d] = sd;
#pragma unroll
    for (int n = 0; n < 16; ++n)
        S_end[(((size_t)c * BATCH + b) * 16 + n) * D_INNER + d] = s[n];
}

// Thread per (b,d,n); in-place: S holds end-states on entry, init-states on exit.
__global__ __launch_bounds__(256)
void scan2(const float* __restrict__ sum_delta, float* __restrict__ S,
           const float* __restrict__ A_log) {
    const int idx = blockIdx.x * 256 + threadIdx.x;   // [0, BATCH*16*D_INNER)
    const int d = idx & (D_INNER - 1);
    const int n = (idx >> 11) & 15;
    const int b = idx >> 15;
    const float A = -__expf(A_log[(size_t)d * 16 + n]);
    float carry = 0.f;
    for (int c = 0; c < NCH; ++c) {
        const float sd = sum_delta[((size_t)c * BATCH + b) * D_INNER + d];
        const size_t o = (((size_t)c * BATCH + b) * 16 + n) * D_INNER + d;
        const float se = S[o];
        S[o] = carry;
        carry = fmaf(carry, __expf(sd * A), se);
    }
}

__global__ __launch_bounds__(256)
void scan3(float* __restrict__ delta /* in: delta, out: gated y */,
           const short* __restrict__ xchi, const short* __restrict__ xclo,
           const float* __restrict__ z, const float* __restrict__ dtbc,
           const float* __restrict__ A_log, const float* __restrict__ S_init,
           const float* __restrict__ Dp) {
    const int d = blockIdx.x * 256 + threadIdx.x;
    const int b = blockIdx.y;
    const int c = blockIdx.z;
    __shared__ float bc[CH][32];
    for (int i = threadIdx.x; i < CH * 32; i += 256) {
        const int row = i >> 5, col = i & 31;
        bc[row][col] = dtbc[(size_t)(b * SEQLEN + c * CH + row) * NPROJ + DT_RANK + col];
    }
    __syncthreads();
    float A[16];
#pragma unroll
    for (int n = 0; n < 16; ++n) A[n] = -__expf(A_log[(size_t)d * 16 + n]);
    float s[16];
#pragma unroll
    for (int n = 0; n < 16; ++n)
        s[n] = S_init[(((size_t)c * BATCH + b) * 16 + n) * D_INNER + d];
    const float Dv = Dp[d];
    const size_t base = ((size_t)b * SEQLEN + (size_t)c * CH) * D_INNER + d;
    for (int li = 0; li < CH; ++li) {
        const size_t o = base + (size_t)li * D_INNER;
        const float dl = delta[o];
        const float xv = bf2f(xchi[o]) + bf2f(xclo[o]);
        const float dx = dl * xv;
        float y = 0.f;
#pragma unroll
        for (int n = 0; n < 16; ++n) {
            const float a = __expf(dl * A[n]);
            s[n] = fmaf(s[n], a, dx * bc[li][n]);
            y = fmaf(s[n], bc[li][16 + n], y);
        }
        const float zv = z[o];
        delta[o] = (y + Dv * xv) * (zv * sigmoidf_(zv));
    }
}

// ---------------------------------------------------------------------------
extern "C" void kernel_launch(void* const* d_in, const int* in_sizes, int n_in,
                              void* d_out, int out_size, void* d_ws, size_t ws_size,
                              hipStream_t stream) {
    const float* hidden   = (const float*)d_in[0];
    const float* W_in     = (const float*)d_in[1];
    const float* conv_w   = (const float*)d_in[2];
    const float* conv_b   = (const float*)d_in[3];
    const float* x_proj_w = (const float*)d_in[4];
    const float* dt_w     = (const float*)d_in[5];
    const float* dt_b     = (const float*)d_in[6];
    const float* A_log    = (const float*)d_in[7];
    const float* Dp       = (const float*)d_in[8];
    const float* W_out    = (const float*)d_in[9];
    float* out = (float*)d_out;

    // Workspace (floats), peak ~223 MB:
    float* ws    = (float*)d_ws;
    float* xbuf  = ws;                                    // BL*D_INNER (x; delta; y)
    float* zbuf  = xbuf + (size_t)BL * D_INNER;           // BL*D_INNER (z; later y hi/lo)
    float* xcreg = zbuf + (size_t)BL * D_INNER;           // BL*D_INNER bytes region
    float* dtbc  = xcreg + (size_t)BL * D_INNER;          // BL*NPROJ
    float* sumd  = dtbc + (size_t)BL * NPROJ;             // NCH*BATCH*D_INNER
    float* Send  = sumd + (size_t)NCH * BATCH * D_INNER;  // NCH*BATCH*16*D_INNER
    float* xpw   = Send + (size_t)NCH * BATCH * 16 * D_INNER; // 96*2048 hi/lo shorts

    // Phase A: bf16 splits of hidden/W_in live in xcreg (dead until conv writes it)
    short* hxhi  = (short*)xcreg;                          // BL*D_MODEL
    short* hxlo  = hxhi + (size_t)BL * D_MODEL;
    short* winhi = hxlo + (size_t)BL * D_MODEL;            // 2*D_INNER*D_MODEL
    short* winlo = winhi + (size_t)2 * D_INNER * D_MODEL;  // 25.2M shorts < 33.5M cap
    short* xpwhi = (short*)xpw;                            // NPROJ*D_INNER
    short* xpwlo = xpwhi + (size_t)NPROJ * D_INNER;

    const dim3 thr(256);

    // 0) split-convert hidden, W_in, x_proj_w to bf16 hi/lo
    cvt_split<<<dim3(BL * D_MODEL / 1024), thr, 0, stream>>>(hidden, hxhi, hxlo, BL * D_MODEL / 4);
    cvt_split<<<dim3(2 * D_INNER * D_MODEL / 1024), thr, 0, stream>>>(W_in, winhi, winlo, 2 * D_INNER * D_MODEL / 4);
    cvt_split<<<dim3(NPROJ * D_INNER / 1024), thr, 0, stream>>>(x_proj_w, xpwhi, xpwlo, NPROJ * D_INNER / 4);

    // 1a) x = hidden @ W_in[even rows]^T  (ldb = 2*D_MODEL row-stride trick)
    gemm_bf16x3<<<dim3(D_INNER / 128, BL / 128), thr, 0, stream>>>(
        hxhi, hxlo, winhi, winlo, xbuf, D_MODEL, D_MODEL, 2 * D_MODEL, D_INNER);
    // 1b) z = hidden @ W_in[odd rows]^T
    gemm_bf16x3<<<dim3(D_INNER / 128, BL / 128), thr, 0, stream>>>(
        hxhi, hxlo, winhi + D_MODEL, winlo + D_MODEL, zbuf, D_MODEL, D_MODEL, 2 * D_MODEL, D_INNER);

    // 2) depthwise causal conv + bias + SiLU -> xc hi/lo (overwrites hx/win)
    short* xchi = (short*)xcreg;
    short* xclo = xchi + (size_t)BL * D_INNER;
    conv_silu_k<<<dim3(BL * D_INNER / 256), thr, 0, stream>>>(xbuf, conv_w, conv_b, xchi, xclo);

    // 3) x_dbl = xc @ x_proj_w^T  (MFMA bf16x3, N=96)
    gemm96<<<dim3(BL / 32), thr, 0, stream>>>(xchi, xclo, xpwhi, xpwlo, dtbc);

    // 4) delta = softplus(dt @ dt_w^T + dt_b) -> xbuf (pre-conv x is dead)
    gemm_nt<1><<<dim3(D_INNER / 64, BL / 64), thr, 0, stream>>>(
        dtbc, dt_w, xbuf, BL, D_INNER, DT_RANK, NPROJ, DT_RANK, D_INNER, dt_b);

    // 5-7) chunked selective scan; scan3 writes gated y into xbuf
    scan1<<<dim3(D_INNER / 256, BATCH, NCH), thr, 0, stream>>>(
        xbuf, xchi, xclo, dtbc, A_log, sumd, Send);
    scan2<<<dim3(BATCH * 16 * D_INNER / 256), thr, 0, stream>>>(sumd, Send, A_log);
    scan3<<<dim3(D_INNER / 256, BATCH, NCH), thr, 0, stream>>>(
        xbuf, xchi, xclo, zbuf, dtbc, A_log, Send, Dp);

    // 8) split-convert y -> zbuf region, W_out -> xcreg (both dead)
    short* yhi  = (short*)zbuf;
    short* ylo  = yhi + (size_t)BL * D_INNER;
    short* wohi = (short*)xcreg;
    short* wolo = wohi + (size_t)D_MODEL * D_INNER;
    cvt_split<<<dim3(BL * D_INNER / 1024), thr, 0, stream>>>(xbuf, yhi, ylo, BL * D_INNER / 4);
    cvt_split<<<dim3(D_MODEL * D_INNER / 1024), thr, 0, stream>>>(W_out, wohi, wolo, D_MODEL * D_INNER / 4);

    // 9) out = y2 @ W_out^T
    gemm_bf16x3<<<dim3(D_MODEL / 128, BL / 128), thr, 0, stream>>>(
        yhi, ylo, wohi, wolo, out, D_INNER, D_INNER, D_INNER, D_MODEL);
}

// Round 6
// 762.900 us; speedup vs baseline: 2.4062x; 1.0357x over previous
//
#include <hip/hip_runtime.h>
#include <hip/hip_bf16.h>

#define D_MODEL 1024
#define D_INNER 2048
#define D_STATE 16
#define DT_RANK 64
#define BATCH 2
#define SEQLEN 4096
#define BL (BATCH * SEQLEN)           // 8192 rows (b,l)
#define NPROJ (DT_RANK + 2 * D_STATE) // 96
#define CH 64                         // scan chunk length
#define NCH (SEQLEN / CH)             // 64 chunks

typedef __attribute__((ext_vector_type(8))) short bf16x8;
typedef __attribute__((ext_vector_type(4))) float f32x4;
struct S4 { short x, y, z, w; };

__device__ __forceinline__ float sigmoidf_(float v) {
    return 1.0f / (1.0f + __expf(-v));
}

__device__ __forceinline__ unsigned short bf16_rne(float f) {
    unsigned u = __float_as_uint(f);
    unsigned r = u + 0x7FFFu + ((u >> 16) & 1u);
    return (unsigned short)(r >> 16);
}

__device__ __forceinline__ float bf2f(short s) {
    return __uint_as_float(((unsigned)(unsigned short)s) << 16);
}

// ---------------------------------------------------------------------------
// Split fp32 -> bf16 hi + bf16 lo (lo = rne(x - hi)); rel err ~2^-17.
// ---------------------------------------------------------------------------
__global__ __launch_bounds__(256)
void cvt_split(const float* __restrict__ in, short* __restrict__ hi,
               short* __restrict__ lo, int n4) {
    const int i = blockIdx.x * 256 + threadIdx.x;
    if (i >= n4) return;
    const float4 v = reinterpret_cast<const float4*>(in)[i];
    const float f[4] = {v.x, v.y, v.z, v.w};
    S4 h, l;
    short hb[4], lb[4];
#pragma unroll
    for (int j = 0; j < 4; ++j) {
        const unsigned short hh = bf16_rne(f[j]);
        const float hf = __uint_as_float((unsigned)hh << 16);
        hb[j] = (short)hh;
        lb[j] = (short)bf16_rne(f[j] - hf);
    }
    h.x = hb[0]; h.y = hb[1]; h.z = hb[2]; h.w = hb[3];
    l.x = lb[0]; l.y = lb[1]; l.z = lb[2]; l.w = lb[3];
    *reinterpret_cast<S4*>(hi + (size_t)i * 4) = h;
    *reinterpret_cast<S4*>(lo + (size_t)i * 4) = l;
}

// ---------------------------------------------------------------------------
// bf16x3 split-precision MFMA NT GEMM. 128x128 tile, BK=32, 4 waves (one
// stages each of Ahi/Alo/Bhi/Blo via global_load_lds width 16).
// T1: XCD-aware block swizzle. T2: LDS XOR-swizzle via pre-swizzled global
// source (linear LDS dest) + matching swizzled ds_read: k-chunk' = kc ^
// ((row>>1)&3) -> 16-lane column read spreads over 8 bank slots (2-way, free).
// EPI: 0 = plain store, 1 = softplus(v + bias[n]).
// Requires M%128==0, N%128==0, K%32==0.
// ---------------------------------------------------------------------------
template <int EPI>
__global__ __launch_bounds__(256)
void gemm_bf16x3(const short* __restrict__ Ahi, const short* __restrict__ Alo,
                 const short* __restrict__ Bhi, const short* __restrict__ Blo,
                 float* __restrict__ C, int K, int lda, int ldb, int ldc,
                 const float* __restrict__ bias) {
    __shared__ short sA[2][128][32];  // [hi/lo][row][k] (k-chunks XOR-swizzled)
    __shared__ short sB[2][128][32];
    const int t = threadIdx.x;
    const int w = t >> 6, l = t & 63;

    // XCD swizzle (grid % 8 == 0 for all callers)
    const int nwg = gridDim.x * gridDim.y;
    int bid = blockIdx.y * gridDim.x + blockIdx.x;
    if ((nwg & 7) == 0) bid = (bid & 7) * (nwg >> 3) + (bid >> 3);
    const int m0 = (bid / gridDim.x) * 128, n0 = (bid % gridDim.x) * 128;
    const int wr = w >> 1, wc = w & 1;

    // staging assignment: wave 0->Ahi, 1->Alo, 2->Bhi, 3->Blo
    const short* gsrc;
    short* sdst;
    int ld, tile0;
    if (w == 0)      { gsrc = Ahi; sdst = &sA[0][0][0]; tile0 = m0; ld = lda; }
    else if (w == 1) { gsrc = Alo; sdst = &sA[1][0][0]; tile0 = m0; ld = lda; }
    else if (w == 2) { gsrc = Bhi; sdst = &sB[0][0][0]; tile0 = n0; ld = ldb; }
    else             { gsrc = Blo; sdst = &sB[1][0][0]; tile0 = n0; ld = ldb; }
    // T2: pre-swizzle the SOURCE k-chunk; invariant under the +16-row stepping
    const int kc_src = ((l & 3) ^ ((l >> 3) & 3)) << 3;
    const size_t grow = (size_t)(tile0 + (l >> 2)) * ld + kc_src;

    f32x4 acc[4][4] = {};
    const int frow = l & 15;
    // T2: swizzled read chunk (row parity term (row>>1)&3 == (frow>>1)&3
    // because wr*64 and f*16 contribute multiples of 4 after >>1)
    const int kb = (((l >> 4) ^ ((frow >> 1) & 3)) << 3);

    for (int k0 = 0; k0 < K; k0 += 32) {
        __syncthreads();
#pragma unroll
        for (int i = 0; i < 8; ++i) {
            const short* g = gsrc + grow + (size_t)(i << 4) * ld + k0;
            __builtin_amdgcn_global_load_lds(
                (const __attribute__((address_space(1))) void*)g,
                (__attribute__((address_space(3))) void*)(sdst + (i << 9)),
                16, 0, 0);
        }
        __syncthreads();

        bf16x8 a[2][4], b[2][4];
#pragma unroll
        for (int f = 0; f < 4; ++f) {
            a[0][f] = *reinterpret_cast<const bf16x8*>(&sA[0][wr * 64 + f * 16 + frow][kb]);
            a[1][f] = *reinterpret_cast<const bf16x8*>(&sA[1][wr * 64 + f * 16 + frow][kb]);
            b[0][f] = *reinterpret_cast<const bf16x8*>(&sB[0][wc * 64 + f * 16 + frow][kb]);
            b[1][f] = *reinterpret_cast<const bf16x8*>(&sB[1][wc * 64 + f * 16 + frow][kb]);
        }
#pragma unroll
        for (int fi = 0; fi < 4; ++fi)
#pragma unroll
            for (int fj = 0; fj < 4; ++fj) {
                acc[fi][fj] = __builtin_amdgcn_mfma_f32_16x16x32_bf16(
                    a[0][fi], b[0][fj], acc[fi][fj], 0, 0, 0);
                acc[fi][fj] = __builtin_amdgcn_mfma_f32_16x16x32_bf16(
                    a[1][fi], b[0][fj], acc[fi][fj], 0, 0, 0);
                acc[fi][fj] = __builtin_amdgcn_mfma_f32_16x16x32_bf16(
                    a[0][fi], b[1][fj], acc[fi][fj], 0, 0, 0);
            }
    }

    // C/D layout (m89-verified): col = lane&15, row = (lane>>4)*4 + reg
    const int crow = (l >> 4) << 2;
    const int ccol = l & 15;
#pragma unroll
    for (int fi = 0; fi < 4; ++fi)
#pragma unroll
        for (int fj = 0; fj < 4; ++fj) {
            const int n = n0 + wc * 64 + fj * 16 + ccol;
#pragma unroll
            for (int r = 0; r < 4; ++r) {
                float v = acc[fi][fj][r];
                if (EPI == 1) {
                    v += bias[n];
                    v = fmaxf(v, 0.f) + log1pf(__expf(-fabsf(v)));  // stable softplus
                }
                C[(size_t)(m0 + wr * 64 + fi * 16 + crow + r) * ldc + n] = v;
            }
        }
}

// ---------------------------------------------------------------------------
// Tall-skinny bf16x3 MFMA GEMM for x_proj: C[BL x 96] = X[BL x 2048]*W[96 x 2048]^T.
// No LDS: fragments loaded directly from global (W is L2 resident).
// Also emits the dt columns (0..63) as bf16 hi/lo for the delta GEMM.
// ---------------------------------------------------------------------------
__global__ __launch_bounds__(256)
void gemm96(const short* __restrict__ Xhi, const short* __restrict__ Xlo,
            const short* __restrict__ Whi, const short* __restrict__ Wlo,
            float* __restrict__ C, short* __restrict__ dthi,
            short* __restrict__ dtlo) {
    const int t = threadIdx.x;
    const int w = t >> 6, l = t & 63;
    const int m0 = blockIdx.x * 32;
    const int rfrag = (w >> 1) * 16;     // row-frag base within tile
    const int cbase = (w & 1) * 48;      // col base (3 frags of 16)
    const int lrow = l & 15;
    const int koff0 = (l >> 4) << 3;     // 0,8,16,24
    f32x4 acc[3] = {};
    const size_t arow = (size_t)(m0 + rfrag + lrow) * D_INNER;
#pragma unroll 2
    for (int k0 = 0; k0 < D_INNER; k0 += 32) {
        const int ko = k0 + koff0;
        const bf16x8 ah = *reinterpret_cast<const bf16x8*>(Xhi + arow + ko);
        const bf16x8 al = *reinterpret_cast<const bf16x8*>(Xlo + arow + ko);
#pragma unroll
        for (int jj = 0; jj < 3; ++jj) {
            const size_t brow = (size_t)(cbase + jj * 16 + lrow) * D_INNER + ko;
            const bf16x8 bh = *reinterpret_cast<const bf16x8*>(Whi + brow);
            const bf16x8 bl = *reinterpret_cast<const bf16x8*>(Wlo + brow);
            acc[jj] = __builtin_amdgcn_mfma_f32_16x16x32_bf16(ah, bh, acc[jj], 0, 0, 0);
            acc[jj] = __builtin_amdgcn_mfma_f32_16x16x32_bf16(al, bh, acc[jj], 0, 0, 0);
            acc[jj] = __builtin_amdgcn_mfma_f32_16x16x32_bf16(ah, bl, acc[jj], 0, 0, 0);
        }
    }
    const int crow = (l >> 4) << 2;
#pragma unroll
    for (int jj = 0; jj < 3; ++jj) {
        const int col = cbase + jj * 16 + lrow;
#pragma unroll
        for (int r = 0; r < 4; ++r) {
            const int m = m0 + rfrag + crow + r;
            const float v = acc[jj][r];
            C[(size_t)m * NPROJ + col] = v;
            if (col < DT_RANK) {  // uniform per frag (cbase+jj*16 multiple of 16)
                const unsigned short hh = bf16_rne(v);
                dthi[(size_t)m * DT_RANK + col] = (short)hh;
                dtlo[(size_t)m * DT_RANK + col] =
                    (short)bf16_rne(v - __uint_as_float((unsigned)hh << 16));
            }
        }
    }
}

// ---------------------------------------------------------------------------
// Depthwise causal conv (D_CONV=4) + bias + SiLU -> bf16 hi/lo split output.
// ---------------------------------------------------------------------------
__global__ __launch_bounds__(256)
void conv_silu_k(const float* __restrict__ xr, const float* __restrict__ cw,
                 const float* __restrict__ cb, short* __restrict__ xchi,
                 short* __restrict__ xclo) {
    const int idx = blockIdx.x * 256 + threadIdx.x;
    const int d = idx & (D_INNER - 1);
    const int bl = idx >> 11;
    const int l = bl & (SEQLEN - 1);
    const float4 w4 = *reinterpret_cast<const float4*>(cw + (size_t)d * 4);
    const float wj[4] = {w4.x, w4.y, w4.z, w4.w};
    float acc = cb[d];
#pragma unroll
    for (int j = 0; j < 4; ++j) {
        const int ll = l - 3 + j;
        if (ll >= 0)
            acc += xr[(size_t)(bl - 3 + j) * D_INNER + d] * wj[j];
    }
    const float v = acc * sigmoidf_(acc);
    const unsigned short hh = bf16_rne(v);
    xchi[idx] = (short)hh;
    xclo[idx] = (short)bf16_rne(v - __uint_as_float((unsigned)hh << 16));
}

// ---------------------------------------------------------------------------
// Selective scan, chunked 3-pass. x reconstructed from bf16 hi/lo (err 2^-17).
// ---------------------------------------------------------------------------
__global__ __launch_bounds__(256)
void scan1(const float* __restrict__ delta, const short* __restrict__ xchi,
           const short* __restrict__ xclo, const float* __restrict__ dtbc,
           const float* __restrict__ A_log, float* __restrict__ sum_delta,
           float* __restrict__ S_end) {
    const int d = blockIdx.x * 256 + threadIdx.x;
    const int b = blockIdx.y;
    const int c = blockIdx.z;
    __shared__ float bc[CH][32];
    for (int i = threadIdx.x; i < CH * 32; i += 256) {
        const int row = i >> 5, col = i & 31;
        bc[row][col] = dtbc[(size_t)(b * SEQLEN + c * CH + row) * NPROJ + DT_RANK + col];
    }
    __syncthreads();
    float A[16];
#pragma unroll
    for (int n = 0; n < 16; ++n) A[n] = -__expf(A_log[(size_t)d * 16 + n]);
    float s[16] = {0.f};
    float sd = 0.f;
    const size_t base = ((size_t)b * SEQLEN + (size_t)c * CH) * D_INNER + d;
    for (int li = 0; li < CH; ++li) {
        const size_t o = base + (size_t)li * D_INNER;
        const float dl = delta[o];
        const float xv = bf2f(xchi[o]) + bf2f(xclo[o]);
        sd += dl;
        const float dx = dl * xv;
#pragma unroll
        for (int n = 0; n < 16; ++n) {
            const float a = __expf(dl * A[n]);
            s[n] = fmaf(s[n], a, dx * bc[li][n]);
        }
    }
    sum_delta[((size_t)c * BATCH + b) * D_INNER + d] = sd;
#pragma unroll
    for (int n = 0; n < 16; ++n)
        S_end[(((size_t)c * BATCH + b) * 16 + n) * D_INNER + d] = s[n];
}

// Thread per (b,d,n); in-place: S holds end-states on entry, init-states on exit.
__global__ __launch_bounds__(256)
void scan2(const float* __restrict__ sum_delta, float* __restrict__ S,
           const float* __restrict__ A_log) {
    const int idx = blockIdx.x * 256 + threadIdx.x;   // [0, BATCH*16*D_INNER)
    const int d = idx & (D_INNER - 1);
    const int n = (idx >> 11) & 15;
    const int b = idx >> 15;
    const float A = -__expf(A_log[(size_t)d * 16 + n]);
    float carry = 0.f;
    for (int c = 0; c < NCH; ++c) {
        const float sd = sum_delta[((size_t)c * BATCH + b) * D_INNER + d];
        const size_t o = (((size_t)c * BATCH + b) * 16 + n) * D_INNER + d;
        const float se = S[o];
        S[o] = carry;
        carry = fmaf(carry, __expf(sd * A), se);
    }
}

// scan3: reads delta/xc/z; writes gated y as bf16 hi/lo IN-PLACE over xchi/xclo
// (each element touched only by its owning thread -> no cross-thread hazard).
__global__ __launch_bounds__(256)
void scan3(const float* __restrict__ delta, short* __restrict__ xchi,
           short* __restrict__ xclo, const float* __restrict__ z,
           const float* __restrict__ dtbc, const float* __restrict__ A_log,
           const float* __restrict__ S_init, const float* __restrict__ Dp) {
    const int d = blockIdx.x * 256 + threadIdx.x;
    const int b = blockIdx.y;
    const int c = blockIdx.z;
    __shared__ float bc[CH][32];
    for (int i = threadIdx.x; i < CH * 32; i += 256) {
        const int row = i >> 5, col = i & 31;
        bc[row][col] = dtbc[(size_t)(b * SEQLEN + c * CH + row) * NPROJ + DT_RANK + col];
    }
    __syncthreads();
    float A[16];
#pragma unroll
    for (int n = 0; n < 16; ++n) A[n] = -__expf(A_log[(size_t)d * 16 + n]);
    float s[16];
#pragma unroll
    for (int n = 0; n < 16; ++n)
        s[n] = S_init[(((size_t)c * BATCH + b) * 16 + n) * D_INNER + d];
    const float Dv = Dp[d];
    const size_t base = ((size_t)b * SEQLEN + (size_t)c * CH) * D_INNER + d;
    for (int li = 0; li < CH; ++li) {
        const size_t o = base + (size_t)li * D_INNER;
        const float dl = delta[o];
        const float xv = bf2f(xchi[o]) + bf2f(xclo[o]);
        const float dx = dl * xv;
        float y = 0.f;
#pragma unroll
        for (int n = 0; n < 16; ++n) {
            const float a = __expf(dl * A[n]);
            s[n] = fmaf(s[n], a, dx * bc[li][n]);
            y = fmaf(s[n], bc[li][16 + n], y);
        }
        const float zv = z[o];
        const float yv = (y + Dv * xv) * (zv * sigmoidf_(zv));
        const unsigned short hh = bf16_rne(yv);
        xchi[o] = (short)hh;
        xclo[o] = (short)bf16_rne(yv - __uint_as_float((unsigned)hh << 16));
    }
}

// ---------------------------------------------------------------------------
extern "C" void kernel_launch(void* const* d_in, const int* in_sizes, int n_in,
                              void* d_out, int out_size, void* d_ws, size_t ws_size,
                              hipStream_t stream) {
    const float* hidden   = (const float*)d_in[0];
    const float* W_in     = (const float*)d_in[1];
    const float* conv_w   = (const float*)d_in[2];
    const float* conv_b   = (const float*)d_in[3];
    const float* x_proj_w = (const float*)d_in[4];
    const float* dt_w     = (const float*)d_in[5];
    const float* dt_b     = (const float*)d_in[6];
    const float* A_log    = (const float*)d_in[7];
    const float* Dp       = (const float*)d_in[8];
    const float* W_out    = (const float*)d_in[9];
    float* out = (float*)d_out;

    // Workspace (floats), peak ~226 MB:
    float* ws    = (float*)d_ws;
    float* xbuf  = ws;                                    // BL*D_INNER (x; delta)
    float* zbuf  = xbuf + (size_t)BL * D_INNER;           // BL*D_INNER (z; later W_out hi/lo)
    float* xcreg = zbuf + (size_t)BL * D_INNER;           // BL*D_INNER (hid/W_in splits; xc hi/lo; y hi/lo)
    float* dtbc  = xcreg + (size_t)BL * D_INNER;          // BL*NPROJ
    float* sumd  = dtbc + (size_t)BL * NPROJ;             // NCH*BATCH*D_INNER
    float* Send  = sumd + (size_t)NCH * BATCH * D_INNER;  // NCH*BATCH*16*D_INNER

    short* xpwhi = (short*)(Send + (size_t)NCH * BATCH * 16 * D_INNER);
    short* xpwlo = xpwhi + (size_t)NPROJ * D_INNER;
    short* dtwhi = xpwlo + (size_t)NPROJ * D_INNER;       // dt_w split
    short* dtwlo = dtwhi + (size_t)D_INNER * DT_RANK;
    short* dthi  = dtwlo + (size_t)D_INNER * DT_RANK;     // dt (x_dbl cols 0..63) split
    short* dtlo  = dthi + (size_t)BL * DT_RANK;

    // Phase A: bf16 splits of hidden/W_in live in xcreg (dead until conv writes it)
    short* hxhi  = (short*)xcreg;                          // BL*D_MODEL
    short* hxlo  = hxhi + (size_t)BL * D_MODEL;
    short* winhi = hxlo + (size_t)BL * D_MODEL;            // 2*D_INNER*D_MODEL
    short* winlo = winhi + (size_t)2 * D_INNER * D_MODEL;  // 25.2M shorts < 33.5M cap

    const dim3 thr(256);

    // 0) split-convert hidden, W_in, x_proj_w, dt_w to bf16 hi/lo
    cvt_split<<<dim3(BL * D_MODEL / 1024), thr, 0, stream>>>(hidden, hxhi, hxlo, BL * D_MODEL / 4);
    cvt_split<<<dim3(2 * D_INNER * D_MODEL / 1024), thr, 0, stream>>>(W_in, winhi, winlo, 2 * D_INNER * D_MODEL / 4);
    cvt_split<<<dim3(NPROJ * D_INNER / 1024), thr, 0, stream>>>(x_proj_w, xpwhi, xpwlo, NPROJ * D_INNER / 4);
    cvt_split<<<dim3(D_INNER * DT_RANK / 1024), thr, 0, stream>>>(dt_w, dtwhi, dtwlo, D_INNER * DT_RANK / 4);

    // 1a) x = hidden @ W_in[even rows]^T  (ldb = 2*D_MODEL row-stride trick)
    gemm_bf16x3<0><<<dim3(D_INNER / 128, BL / 128), thr, 0, stream>>>(
        hxhi, hxlo, winhi, winlo, xbuf, D_MODEL, D_MODEL, 2 * D_MODEL, D_INNER, nullptr);
    // 1b) z = hidden @ W_in[odd rows]^T
    gemm_bf16x3<0><<<dim3(D_INNER / 128, BL / 128), thr, 0, stream>>>(
        hxhi, hxlo, winhi + D_MODEL, winlo + D_MODEL, zbuf, D_MODEL, D_MODEL, 2 * D_MODEL, D_INNER, nullptr);

    // 2) depthwise causal conv + bias + SiLU -> xc hi/lo (overwrites hx/win)
    short* xchi = (short*)xcreg;
    short* xclo = xchi + (size_t)BL * D_INNER;
    conv_silu_k<<<dim3(BL * D_INNER / 256), thr, 0, stream>>>(xbuf, conv_w, conv_b, xchi, xclo);

    // 3) x_dbl = xc @ x_proj_w^T (MFMA bf16x3, N=96) + dt bf16 split emit
    gemm96<<<dim3(BL / 32), thr, 0, stream>>>(xchi, xclo, xpwhi, xpwlo, dtbc, dthi, dtlo);

    // 4) delta = softplus(dt @ dt_w^T + dt_b) -> xbuf  (MFMA bf16x3, K=64)
    gemm_bf16x3<1><<<dim3(D_INNER / 128, BL / 128), thr, 0, stream>>>(
        dthi, dtlo, dtwhi, dtwlo, xbuf, DT_RANK, DT_RANK, DT_RANK, D_INNER, dt_b);

    // 5-7) chunked selective scan; scan3 writes y hi/lo in-place over xchi/xclo
    scan1<<<dim3(D_INNER / 256, BATCH, NCH), thr, 0, stream>>>(
        xbuf, xchi, xclo, dtbc, A_log, sumd, Send);
    scan2<<<dim3(BATCH * 16 * D_INNER / 256), thr, 0, stream>>>(sumd, Send, A_log);
    scan3<<<dim3(D_INNER / 256, BATCH, NCH), thr, 0, stream>>>(
        xbuf, xchi, xclo, zbuf, dtbc, A_log, Send, Dp);

    // 8) split-convert W_out into zbuf (z is dead after scan3)
    short* wohi = (short*)zbuf;
    short* wolo = wohi + (size_t)D_MODEL * D_INNER;
    cvt_split<<<dim3(D_MODEL * D_INNER / 1024), thr, 0, stream>>>(W_out, wohi, wolo, D_MODEL * D_INNER / 4);

    // 9) out = y @ W_out^T  (y hi/lo live in xchi/xclo)
    gemm_bf16x3<0><<<dim3(D_MODEL / 128, BL / 128), thr, 0, stream>>>(
        xchi, xclo, wohi, wolo, out, D_INNER, D_INNER, D_INNER, D_MODEL, nullptr);
}

// Round 7
// 709.441 us; speedup vs baseline: 2.5875x; 1.0754x over previous
//
#include <hip/hip_runtime.h>
#include <hip/hip_bf16.h>

#define D_MODEL 1024
#define D_INNER 2048
#define D_STATE 16
#define DT_RANK 64
#define BATCH 2
#define SEQLEN 4096
#define BL (BATCH * SEQLEN)           // 8192 rows (b,l)
#define NPROJ (DT_RANK + 2 * D_STATE) // 96
#define CH 64                         // scan chunk length
#define NCH (SEQLEN / CH)             // 64 chunks

typedef __attribute__((ext_vector_type(8))) short bf16x8;
typedef __attribute__((ext_vector_type(4))) float f32x4;
struct S4 { short x, y, z, w; };

__device__ __forceinline__ float sigmoidf_(float v) {
    return 1.0f / (1.0f + __expf(-v));
}

__device__ __forceinline__ unsigned short bf16_rne(float f) {
    unsigned u = __float_as_uint(f);
    unsigned r = u + 0x7FFFu + ((u >> 16) & 1u);
    return (unsigned short)(r >> 16);
}

__device__ __forceinline__ float bf2f(short s) {
    return __uint_as_float(((unsigned)(unsigned short)s) << 16);
}

// ---------------------------------------------------------------------------
// Split fp32 -> bf16 hi + bf16 lo (lo = rne(x - hi)); rel err ~2^-17.
// ---------------------------------------------------------------------------
__global__ __launch_bounds__(256)
void cvt_split(const float* __restrict__ in, short* __restrict__ hi,
               short* __restrict__ lo, int n4) {
    const int i = blockIdx.x * 256 + threadIdx.x;
    if (i >= n4) return;
    const float4 v = reinterpret_cast<const float4*>(in)[i];
    const float f[4] = {v.x, v.y, v.z, v.w};
    S4 h, l;
    short hb[4], lb[4];
#pragma unroll
    for (int j = 0; j < 4; ++j) {
        const unsigned short hh = bf16_rne(f[j]);
        const float hf = __uint_as_float((unsigned)hh << 16);
        hb[j] = (short)hh;
        lb[j] = (short)bf16_rne(f[j] - hf);
    }
    h.x = hb[0]; h.y = hb[1]; h.z = hb[2]; h.w = hb[3];
    l.x = lb[0]; l.y = lb[1]; l.z = lb[2]; l.w = lb[3];
    *reinterpret_cast<S4*>(hi + (size_t)i * 4) = h;
    *reinterpret_cast<S4*>(lo + (size_t)i * 4) = l;
}

// ---------------------------------------------------------------------------
// bf16x3 split-precision MFMA NT GEMM. 128x128 tile, BK=32, 4 waves.
// Round 7: double-buffered LDS + counted vmcnt(8) + raw s_barrier (T3/T4):
// STAGE(t+1 -> buf^1) stays in flight across the barrier; vmcnt(8) waits only
// for tile t's 8 loads. Barrier B (after MFMA consumed all ds_reads) protects
// buf[cur] from next iteration's overwrite. No __syncthreads -> no vmcnt(0)
// drain in the main loop.
// T1: XCD-aware block swizzle. T2: XOR swizzle via pre-swizzled global source
// (conflicts measured 0). EPI: 0 = plain store, 1 = softplus(v + bias[n]).
// Requires M%128==0, N%128==0, K%32==0, K>=64.
// ---------------------------------------------------------------------------
template <int EPI>
__global__ __launch_bounds__(256)
void gemm_bf16x3(const short* __restrict__ Ahi, const short* __restrict__ Alo,
                 const short* __restrict__ Bhi, const short* __restrict__ Blo,
                 float* __restrict__ C, int K, int lda, int ldb, int ldc,
                 const float* __restrict__ bias) {
    __shared__ short sA[2][2][128][32];  // [dbuf][hi/lo][row][k]
    __shared__ short sB[2][2][128][32];
    const int t = threadIdx.x;
    const int w = t >> 6, l = t & 63;

    // T1: XCD swizzle (grid % 8 == 0 for all callers)
    const int nwg = gridDim.x * gridDim.y;
    int bid = blockIdx.y * gridDim.x + blockIdx.x;
    if ((nwg & 7) == 0) bid = (bid & 7) * (nwg >> 3) + (bid >> 3);
    const int m0 = (bid / gridDim.x) * 128, n0 = (bid % gridDim.x) * 128;
    const int wr = w >> 1, wc = w & 1;

    // staging assignment: wave 0->Ahi, 1->Alo, 2->Bhi, 3->Blo
    const short* gsrc;
    short* sd0;
    short* sd1;
    int ld, tile0;
    if (w == 0)      { gsrc = Ahi; sd0 = &sA[0][0][0][0]; sd1 = &sA[1][0][0][0]; tile0 = m0; ld = lda; }
    else if (w == 1) { gsrc = Alo; sd0 = &sA[0][1][0][0]; sd1 = &sA[1][1][0][0]; tile0 = m0; ld = lda; }
    else if (w == 2) { gsrc = Bhi; sd0 = &sB[0][0][0][0]; sd1 = &sB[1][0][0][0]; tile0 = n0; ld = ldb; }
    else             { gsrc = Blo; sd0 = &sB[0][1][0][0]; sd1 = &sB[1][1][0][0]; tile0 = n0; ld = ldb; }
    // T2: pre-swizzled SOURCE k-chunk (invariant under +16-row stepping)
    const int kc_src = ((l & 3) ^ ((l >> 3) & 3)) << 3;
    const size_t grow = (size_t)(tile0 + (l >> 2)) * ld + kc_src;

    f32x4 acc[4][4] = {};
    const int frow = l & 15;
    // T2: swizzled read chunk
    const int kb = (((l >> 4) ^ ((frow >> 1) & 3)) << 3);

    auto STAGE = [&](short* sdst, int k0) {
#pragma unroll
        for (int i = 0; i < 8; ++i) {
            const short* g = gsrc + grow + (size_t)(i << 4) * ld + k0;
            __builtin_amdgcn_global_load_lds(
                (const __attribute__((address_space(1))) void*)g,
                (__attribute__((address_space(3))) void*)(sdst + (i << 9)),
                16, 0, 0);
        }
    };

    auto COMPUTE = [&](int cur) {
        bf16x8 a[2][4], b[2][4];
#pragma unroll
        for (int f = 0; f < 4; ++f) {
            a[0][f] = *reinterpret_cast<const bf16x8*>(&sA[cur][0][wr * 64 + f * 16 + frow][kb]);
            a[1][f] = *reinterpret_cast<const bf16x8*>(&sA[cur][1][wr * 64 + f * 16 + frow][kb]);
            b[0][f] = *reinterpret_cast<const bf16x8*>(&sB[cur][0][wc * 64 + f * 16 + frow][kb]);
            b[1][f] = *reinterpret_cast<const bf16x8*>(&sB[cur][1][wc * 64 + f * 16 + frow][kb]);
        }
#pragma unroll
        for (int fi = 0; fi < 4; ++fi)
#pragma unroll
            for (int fj = 0; fj < 4; ++fj) {
                acc[fi][fj] = __builtin_amdgcn_mfma_f32_16x16x32_bf16(
                    a[0][fi], b[0][fj], acc[fi][fj], 0, 0, 0);
                acc[fi][fj] = __builtin_amdgcn_mfma_f32_16x16x32_bf16(
                    a[1][fi], b[0][fj], acc[fi][fj], 0, 0, 0);
                acc[fi][fj] = __builtin_amdgcn_mfma_f32_16x16x32_bf16(
                    a[0][fi], b[1][fj], acc[fi][fj], 0, 0, 0);
            }
    };

    const int NT = K >> 5;
    STAGE(sd0, 0);                           // prologue: tile 0 -> buf0
    for (int tt = 0; tt < NT - 1; ++tt) {
        const int cur = tt & 1;
        STAGE(cur ? sd0 : sd1, (tt + 1) << 5);   // tile tt+1 -> other buf
        __builtin_amdgcn_sched_barrier(0);
        asm volatile("s_waitcnt vmcnt(8)" ::: "memory");  // tile tt's 8 loads done
        __builtin_amdgcn_s_barrier();                     // A: tile tt visible to all
        COMPUTE(cur);
        __builtin_amdgcn_sched_barrier(0);   // keep ds_read/MFMA before barrier B
        __builtin_amdgcn_s_barrier();        // B: buf[cur] free for overwrite
    }
    {   // epilogue tile NT-1 (no further staging)
        const int cur = (NT - 1) & 1;
        __builtin_amdgcn_sched_barrier(0);
        asm volatile("s_waitcnt vmcnt(0)" ::: "memory");
        __builtin_amdgcn_s_barrier();
        COMPUTE(cur);
    }

    // C/D layout (m89-verified): col = lane&15, row = (lane>>4)*4 + reg
    const int crow = (l >> 4) << 2;
    const int ccol = l & 15;
#pragma unroll
    for (int fi = 0; fi < 4; ++fi)
#pragma unroll
        for (int fj = 0; fj < 4; ++fj) {
            const int n = n0 + wc * 64 + fj * 16 + ccol;
#pragma unroll
            for (int r = 0; r < 4; ++r) {
                float v = acc[fi][fj][r];
                if (EPI == 1) {
                    v += bias[n];
                    v = fmaxf(v, 0.f) + log1pf(__expf(-fabsf(v)));  // stable softplus
                }
                C[(size_t)(m0 + wr * 64 + fi * 16 + crow + r) * ldc + n] = v;
            }
        }
}

// ---------------------------------------------------------------------------
// Tall-skinny bf16x3 MFMA GEMM for x_proj: C[BL x 96] = X[BL x 2048]*W[96 x 2048]^T.
// No LDS: fragments loaded directly from global (W is L2 resident).
// Also emits the dt columns (0..63) as bf16 hi/lo for the delta GEMM.
// ---------------------------------------------------------------------------
__global__ __launch_bounds__(256)
void gemm96(const short* __restrict__ Xhi, const short* __restrict__ Xlo,
            const short* __restrict__ Whi, const short* __restrict__ Wlo,
            float* __restrict__ C, short* __restrict__ dthi,
            short* __restrict__ dtlo) {
    const int t = threadIdx.x;
    const int w = t >> 6, l = t & 63;
    const int m0 = blockIdx.x * 32;
    const int rfrag = (w >> 1) * 16;     // row-frag base within tile
    const int cbase = (w & 1) * 48;      // col base (3 frags of 16)
    const int lrow = l & 15;
    const int koff0 = (l >> 4) << 3;     // 0,8,16,24
    f32x4 acc[3] = {};
    const size_t arow = (size_t)(m0 + rfrag + lrow) * D_INNER;
#pragma unroll 2
    for (int k0 = 0; k0 < D_INNER; k0 += 32) {
        const int ko = k0 + koff0;
        const bf16x8 ah = *reinterpret_cast<const bf16x8*>(Xhi + arow + ko);
        const bf16x8 al = *reinterpret_cast<const bf16x8*>(Xlo + arow + ko);
#pragma unroll
        for (int jj = 0; jj < 3; ++jj) {
            const size_t brow = (size_t)(cbase + jj * 16 + lrow) * D_INNER + ko;
            const bf16x8 bh = *reinterpret_cast<const bf16x8*>(Whi + brow);
            const bf16x8 bl = *reinterpret_cast<const bf16x8*>(Wlo + brow);
            acc[jj] = __builtin_amdgcn_mfma_f32_16x16x32_bf16(ah, bh, acc[jj], 0, 0, 0);
            acc[jj] = __builtin_amdgcn_mfma_f32_16x16x32_bf16(al, bh, acc[jj], 0, 0, 0);
            acc[jj] = __builtin_amdgcn_mfma_f32_16x16x32_bf16(ah, bl, acc[jj], 0, 0, 0);
        }
    }
    const int crow = (l >> 4) << 2;
#pragma unroll
    for (int jj = 0; jj < 3; ++jj) {
        const int col = cbase + jj * 16 + lrow;
#pragma unroll
        for (int r = 0; r < 4; ++r) {
            const int m = m0 + rfrag + crow + r;
            const float v = acc[jj][r];
            C[(size_t)m * NPROJ + col] = v;
            if (col < DT_RANK) {  // uniform per frag (cbase+jj*16 multiple of 16)
                const unsigned short hh = bf16_rne(v);
                dthi[(size_t)m * DT_RANK + col] = (short)hh;
                dtlo[(size_t)m * DT_RANK + col] =
                    (short)bf16_rne(v - __uint_as_float((unsigned)hh << 16));
            }
        }
    }
}

// ---------------------------------------------------------------------------
// Depthwise causal conv (D_CONV=4) + bias + SiLU -> bf16 hi/lo split output.
// ---------------------------------------------------------------------------
__global__ __launch_bounds__(256)
void conv_silu_k(const float* __restrict__ xr, const float* __restrict__ cw,
                 const float* __restrict__ cb, short* __restrict__ xchi,
                 short* __restrict__ xclo) {
    const int idx = blockIdx.x * 256 + threadIdx.x;
    const int d = idx & (D_INNER - 1);
    const int bl = idx >> 11;
    const int l = bl & (SEQLEN - 1);
    const float4 w4 = *reinterpret_cast<const float4*>(cw + (size_t)d * 4);
    const float wj[4] = {w4.x, w4.y, w4.z, w4.w};
    float acc = cb[d];
#pragma unroll
    for (int j = 0; j < 4; ++j) {
        const int ll = l - 3 + j;
        if (ll >= 0)
            acc += xr[(size_t)(bl - 3 + j) * D_INNER + d] * wj[j];
    }
    const float v = acc * sigmoidf_(acc);
    const unsigned short hh = bf16_rne(v);
    xchi[idx] = (short)hh;
    xclo[idx] = (short)bf16_rne(v - __uint_as_float((unsigned)hh << 16));
}

// ---------------------------------------------------------------------------
// Selective scan, chunked 3-pass. x reconstructed from bf16 hi/lo (err 2^-17).
// ---------------------------------------------------------------------------
__global__ __launch_bounds__(256)
void scan1(const float* __restrict__ delta, const short* __restrict__ xchi,
           const short* __restrict__ xclo, const float* __restrict__ dtbc,
           const float* __restrict__ A_log, float* __restrict__ sum_delta,
           float* __restrict__ S_end) {
    const int d = blockIdx.x * 256 + threadIdx.x;
    const int b = blockIdx.y;
    const int c = blockIdx.z;
    __shared__ float bc[CH][32];
    for (int i = threadIdx.x; i < CH * 32; i += 256) {
        const int row = i >> 5, col = i & 31;
        bc[row][col] = dtbc[(size_t)(b * SEQLEN + c * CH + row) * NPROJ + DT_RANK + col];
    }
    __syncthreads();
    float A[16];
#pragma unroll
    for (int n = 0; n < 16; ++n) A[n] = -__expf(A_log[(size_t)d * 16 + n]);
    float s[16] = {0.f};
    float sd = 0.f;
    const size_t base = ((size_t)b * SEQLEN + (size_t)c * CH) * D_INNER + d;
    for (int li = 0; li < CH; ++li) {
        const size_t o = base + (size_t)li * D_INNER;
        const float dl = delta[o];
        const float xv = bf2f(xchi[o]) + bf2f(xclo[o]);
        sd += dl;
        const float dx = dl * xv;
#pragma unroll
        for (int n = 0; n < 16; ++n) {
            const float a = __expf(dl * A[n]);
            s[n] = fmaf(s[n], a, dx * bc[li][n]);
        }
    }
    sum_delta[((size_t)c * BATCH + b) * D_INNER + d] = sd;
#pragma unroll
    for (int n = 0; n < 16; ++n)
        S_end[(((size_t)c * BATCH + b) * 16 + n) * D_INNER + d] = s[n];
}

// Thread per (b,d,n); in-place: S holds end-states on entry, init-states on exit.
__global__ __launch_bounds__(256)
void scan2(const float* __restrict__ sum_delta, float* __restrict__ S,
           const float* __restrict__ A_log) {
    const int idx = blockIdx.x * 256 + threadIdx.x;   // [0, BATCH*16*D_INNER)
    const int d = idx & (D_INNER - 1);
    const int n = (idx >> 11) & 15;
    const int b = idx >> 15;
    const float A = -__expf(A_log[(size_t)d * 16 + n]);
    float carry = 0.f;
    for (int c = 0; c < NCH; ++c) {
        const float sd = sum_delta[((size_t)c * BATCH + b) * D_INNER + d];
        const size_t o = (((size_t)c * BATCH + b) * 16 + n) * D_INNER + d;
        const float se = S[o];
        S[o] = carry;
        carry = fmaf(carry, __expf(sd * A), se);
    }
}

// scan3: reads delta/xc/z; writes gated y as bf16 hi/lo IN-PLACE over xchi/xclo
// (each element touched only by its owning thread -> no cross-thread hazard).
__global__ __launch_bounds__(256)
void scan3(const float* __restrict__ delta, short* __restrict__ xchi,
           short* __restrict__ xclo, const float* __restrict__ z,
           const float* __restrict__ dtbc, const float* __restrict__ A_log,
           const float* __restrict__ S_init, const float* __restrict__ Dp) {
    const int d = blockIdx.x * 256 + threadIdx.x;
    const int b = blockIdx.y;
    const int c = blockIdx.z;
    __shared__ float bc[CH][32];
    for (int i = threadIdx.x; i < CH * 32; i += 256) {
        const int row = i >> 5, col = i & 31;
        bc[row][col] = dtbc[(size_t)(b * SEQLEN + c * CH + row) * NPROJ + DT_RANK + col];
    }
    __syncthreads();
    float A[16];
#pragma unroll
    for (int n = 0; n < 16; ++n) A[n] = -__expf(A_log[(size_t)d * 16 + n]);
    float s[16];
#pragma unroll
    for (int n = 0; n < 16; ++n)
        s[n] = S_init[(((size_t)c * BATCH + b) * 16 + n) * D_INNER + d];
    const float Dv = Dp[d];
    const size_t base = ((size_t)b * SEQLEN + (size_t)c * CH) * D_INNER + d;
    for (int li = 0; li < CH; ++li) {
        const size_t o = base + (size_t)li * D_INNER;
        const float dl = delta[o];
        const float xv = bf2f(xchi[o]) + bf2f(xclo[o]);
        const float dx = dl * xv;
        float y = 0.f;
#pragma unroll
        for (int n = 0; n < 16; ++n) {
            const float a = __expf(dl * A[n]);
            s[n] = fmaf(s[n], a, dx * bc[li][n]);
            y = fmaf(s[n], bc[li][16 + n], y);
        }
        const float zv = z[o];
        const float yv = (y + Dv * xv) * (zv * sigmoidf_(zv));
        const unsigned short hh = bf16_rne(yv);
        xchi[o] = (short)hh;
        xclo[o] = (short)bf16_rne(yv - __uint_as_float((unsigned)hh << 16));
    }
}

// ---------------------------------------------------------------------------
extern "C" void kernel_launch(void* const* d_in, const int* in_sizes, int n_in,
                              void* d_out, int out_size, void* d_ws, size_t ws_size,
                              hipStream_t stream) {
    const float* hidden   = (const float*)d_in[0];
    const float* W_in     = (const float*)d_in[1];
    const float* conv_w   = (const float*)d_in[2];
    const float* conv_b   = (const float*)d_in[3];
    const float* x_proj_w = (const float*)d_in[4];
    const float* dt_w     = (const float*)d_in[5];
    const float* dt_b     = (const float*)d_in[6];
    const float* A_log    = (const float*)d_in[7];
    const float* Dp       = (const float*)d_in[8];
    const float* W_out    = (const float*)d_in[9];
    float* out = (float*)d_out;

    // Workspace (floats), peak ~226 MB:
    float* ws    = (float*)d_ws;
    float* xbuf  = ws;                                    // BL*D_INNER (x; delta)
    float* zbuf  = xbuf + (size_t)BL * D_INNER;           // BL*D_INNER (z; later W_out hi/lo)
    float* xcreg = zbuf + (size_t)BL * D_INNER;           // BL*D_INNER (hid/W_in splits; xc hi/lo; y hi/lo)
    float* dtbc  = xcreg + (size_t)BL * D_INNER;          // BL*NPROJ
    float* sumd  = dtbc + (size_t)BL * NPROJ;             // NCH*BATCH*D_INNER
    float* Send  = sumd + (size_t)NCH * BATCH * D_INNER;  // NCH*BATCH*16*D_INNER

    short* xpwhi = (short*)(Send + (size_t)NCH * BATCH * 16 * D_INNER);
    short* xpwlo = xpwhi + (size_t)NPROJ * D_INNER;
    short* dtwhi = xpwlo + (size_t)NPROJ * D_INNER;       // dt_w split
    short* dtwlo = dtwhi + (size_t)D_INNER * DT_RANK;
    short* dthi  = dtwlo + (size_t)D_INNER * DT_RANK;     // dt (x_dbl cols 0..63) split
    short* dtlo  = dthi + (size_t)BL * DT_RANK;

    // Phase A: bf16 splits of hidden/W_in live in xcreg (dead until conv writes it)
    short* hxhi  = (short*)xcreg;                          // BL*D_MODEL
    short* hxlo  = hxhi + (size_t)BL * D_MODEL;
    short* winhi = hxlo + (size_t)BL * D_MODEL;            // 2*D_INNER*D_MODEL
    short* winlo = winhi + (size_t)2 * D_INNER * D_MODEL;  // 25.2M shorts < 33.5M cap

    const dim3 thr(256);

    // 0) split-convert hidden, W_in, x_proj_w, dt_w to bf16 hi/lo
    cvt_split<<<dim3(BL * D_MODEL / 1024), thr, 0, stream>>>(hidden, hxhi, hxlo, BL * D_MODEL / 4);
    cvt_split<<<dim3(2 * D_INNER * D_MODEL / 1024), thr, 0, stream>>>(W_in, winhi, winlo, 2 * D_INNER * D_MODEL / 4);
    cvt_split<<<dim3(NPROJ * D_INNER / 1024), thr, 0, stream>>>(x_proj_w, xpwhi, xpwlo, NPROJ * D_INNER / 4);
    cvt_split<<<dim3(D_INNER * DT_RANK / 1024), thr, 0, stream>>>(dt_w, dtwhi, dtwlo, D_INNER * DT_RANK / 4);

    // 1a) x = hidden @ W_in[even rows]^T  (ldb = 2*D_MODEL row-stride trick)
    gemm_bf16x3<0><<<dim3(D_INNER / 128, BL / 128), thr, 0, stream>>>(
        hxhi, hxlo, winhi, winlo, xbuf, D_MODEL, D_MODEL, 2 * D_MODEL, D_INNER, nullptr);
    // 1b) z = hidden @ W_in[odd rows]^T
    gemm_bf16x3<0><<<dim3(D_INNER / 128, BL / 128), thr, 0, stream>>>(
        hxhi, hxlo, winhi + D_MODEL, winlo + D_MODEL, zbuf, D_MODEL, D_MODEL, 2 * D_MODEL, D_INNER, nullptr);

    // 2) depthwise causal conv + bias + SiLU -> xc hi/lo (overwrites hx/win)
    short* xchi = (short*)xcreg;
    short* xclo = xchi + (size_t)BL * D_INNER;
    conv_silu_k<<<dim3(BL * D_INNER / 256), thr, 0, stream>>>(xbuf, conv_w, conv_b, xchi, xclo);

    // 3) x_dbl = xc @ x_proj_w^T (MFMA bf16x3, N=96) + dt bf16 split emit
    gemm96<<<dim3(BL / 32), thr, 0, stream>>>(xchi, xclo, xpwhi, xpwlo, dtbc, dthi, dtlo);

    // 4) delta = softplus(dt @ dt_w^T + dt_b) -> xbuf  (MFMA bf16x3, K=64)
    gemm_bf16x3<1><<<dim3(D_INNER / 128, BL / 128), thr, 0, stream>>>(
        dthi, dtlo, dtwhi, dtwlo, xbuf, DT_RANK, DT_RANK, DT_RANK, D_INNER, dt_b);

    // 5-7) chunked selective scan; scan3 writes y hi/lo in-place over xchi/xclo
    scan1<<<dim3(D_INNER / 256, BATCH, NCH), thr, 0, stream>>>(
        xbuf, xchi, xclo, dtbc, A_log, sumd, Send);
    scan2<<<dim3(BATCH * 16 * D_INNER / 256), thr, 0, stream>>>(sumd, Send, A_log);
    scan3<<<dim3(D_INNER / 256, BATCH, NCH), thr, 0, stream>>>(
        xbuf, xchi, xclo, zbuf, dtbc, A_log, Send, Dp);

    // 8) split-convert W_out into zbuf (z is dead after scan3)
    short* wohi = (short*)zbuf;
    short* wolo = wohi + (size_t)D_MODEL * D_INNER;
    cvt_split<<<dim3(D_MODEL * D_INNER / 1024), thr, 0, stream>>>(W_out, wohi, wolo, D_MODEL * D_INNER / 4);

    // 9) out = y @ W_out^T  (y hi/lo live in xchi/xclo)
    gemm_bf16x3<0><<<dim3(D_MODEL / 128, BL / 128), thr, 0, stream>>>(
        xchi, xclo, wohi, wolo, out, D_INNER, D_INNER, D_INNER, D_MODEL, nullptr);
}